// Round 1
// baseline (290.367 us; speedup 1.0000x reference)
//
#include <hip/hip_runtime.h>

// GAT: B=4, N=2048, IN=128, HID=64, HEADS=4, OUT=64
#define B_ 4
#define N_ 2048
#define IND_ 128
#define NH_ 4

typedef short short8 __attribute__((ext_vector_type(8)));
typedef float float4v __attribute__((ext_vector_type(4)));

// fp32 -> bf16 bits, round-to-nearest-even (values are finite, no NaN handling needed)
__device__ __forceinline__ unsigned int f2b_bits(float f) {
  unsigned int u = __float_as_uint(f);
  u += 0x7fffu + ((u >> 16) & 1u);
  return u >> 16;
}

// ---- K1: h1[head] = x @ W_heads[head]; s1/t1 = h1 . a_heads halves;
//      h1T = bf16 transposed V operand, layout [(b*4+h)*64 + d][j]  (j contiguous)
__global__ __launch_bounds__(256) void gat_k1(
    const float* __restrict__ x, const float* __restrict__ Wh, const float* __restrict__ ah,
    unsigned short* __restrict__ h1T, float* __restrict__ s1, float* __restrict__ t1) {
  __shared__ float xs[32 * IND_];   // 16 KB x tile (32 rows)
  __shared__ float hl[32 * 257];    // 32.9 KB h tile, +1 pad
  const int b = blockIdx.y, n0 = blockIdx.x * 32;
  const int tid = threadIdx.x;
  const float4* xg = (const float4*)(x + ((size_t)b * N_ + n0) * IND_);
  float4* xs4 = (float4*)xs;
  for (int i = tid; i < 32 * IND_ / 4; i += 256) xs4[i] = xg[i];
  __syncthreads();
  const int h = tid >> 6, d = tid & 63;
  const float* Wp = Wh + h * IND_ * 64 + d;
  float acc[32];
#pragma unroll
  for (int n = 0; n < 32; n++) acc[n] = 0.f;
  for (int k4 = 0; k4 < IND_ / 4; k4++) {
    const float w0 = Wp[(k4 * 4 + 0) * 64];
    const float w1 = Wp[(k4 * 4 + 1) * 64];
    const float w2 = Wp[(k4 * 4 + 2) * 64];
    const float w3 = Wp[(k4 * 4 + 3) * 64];
#pragma unroll
    for (int n = 0; n < 32; n++) {
      float4 xv = xs4[n * (IND_ / 4) + k4];  // broadcast ds_read_b128
      acc[n] = fmaf(xv.x, w0, acc[n]);
      acc[n] = fmaf(xv.y, w1, acc[n]);
      acc[n] = fmaf(xv.z, w2, acc[n]);
      acc[n] = fmaf(xv.w, w3, acc[n]);
    }
  }
#pragma unroll
  for (int n = 0; n < 32; n++) hl[n * 257 + tid] = acc[n];
  __syncthreads();
  if (tid < 128) {  // s/t: one thread per (row, head)
    const int n = tid & 31, hh = tid >> 5;
    const float* hp = hl + n * 257 + hh * 64;
    const float* a1 = ah + hh * 128;
    float sa = 0.f, ta = 0.f;
#pragma unroll 8
    for (int dd = 0; dd < 64; dd++) {
      const float hv = hp[dd];
      sa = fmaf(hv, a1[dd], sa);
      ta = fmaf(hv, a1[64 + dd], ta);
    }
    s1[(b * NH_ + hh) * N_ + n0 + n] = sa;
    t1[(b * NH_ + hh) * N_ + n0 + n] = ta;
  }
  // transposed bf16 pack: thread tid owns h1T row (b*256+tid), writes 32 j's (64 B)
  unsigned int u[16];
#pragma unroll
  for (int i = 0; i < 16; i++)
    u[i] = f2b_bits(hl[(2 * i) * 257 + tid]) | (f2b_bits(hl[(2 * i + 1) * 257 + tid]) << 16);
  unsigned int* dst = (unsigned int*)h1T + (size_t)(b * 256 + tid) * (N_ / 2) + n0 / 2;
#pragma unroll
  for (int g = 0; g < 4; g++)
    ((uint4*)dst)[g] = make_uint4(u[4 * g], u[4 * g + 1], u[4 * g + 2], u[4 * g + 3]);
}

// ---- K2: layer-1 attention. Block = 4 waves = 4 heads, same 16-row i-tile (adj L1 reuse).
// Per 32-j chunk: w = adj ? exp(leaky(s_i+t_j)) : 0 built in A-frag layout, V from h1T as B-frag.
__global__ __launch_bounds__(256) void gat_k2(
    const int* __restrict__ adj, const unsigned short* __restrict__ h1T,
    const float* __restrict__ s1, const float* __restrict__ t1, float* __restrict__ hcat) {
  const int b = blockIdx.y, i0 = blockIdx.x * 16;
  const int tid = threadIdx.x;
  const int h = tid >> 6, lane = tid & 63;
  const int m = lane & 15, q = lane >> 4;
  const float s_i = s1[(b * NH_ + h) * N_ + i0 + m];
  const int* ap = adj + ((size_t)b * N_ + i0 + m) * N_ + q * 8;
  const float* tp = t1 + (b * NH_ + h) * N_ + q * 8;
  const unsigned short* vp = h1T + (size_t)((b * NH_ + h) * 64 + m) * N_ + q * 8;
  float4v acc[4] = {};
  float S = 0.f;
  for (int j0 = 0; j0 < N_; j0 += 32) {
    const int4 a0 = *(const int4*)(ap + j0);
    const int4 a1 = *(const int4*)(ap + j0 + 4);
    const float4 tv0 = *(const float4*)(tp + j0);
    const float4 tv1 = *(const float4*)(tp + j0 + 4);
    const float tv[8] = {tv0.x, tv0.y, tv0.z, tv0.w, tv1.x, tv1.y, tv1.z, tv1.w};
    const int av[8] = {a0.x, a0.y, a0.z, a0.w, a1.x, a1.y, a1.z, a1.w};
    float w[8];
#pragma unroll
    for (int i = 0; i < 8; i++) {
      float e = s_i + tv[i];
      e = fmaxf(e, 0.2f * e);          // leaky_relu, slope 0.2 < 1
      w[i] = av[i] ? __expf(e) : 0.f;  // mask: adj==0 -> weight 0
    }
    S += ((w[0] + w[1]) + (w[2] + w[3])) + ((w[4] + w[5]) + (w[6] + w[7]));
    short8 af;
#pragma unroll
    for (int i = 0; i < 8; i++) af[i] = (short)f2b_bits(w[i]);
#pragma unroll
    for (int dt = 0; dt < 4; dt++) {
      const short8 bf = *(const short8*)(vp + (size_t)dt * 16 * N_ + j0);
      acc[dt] = __builtin_amdgcn_mfma_f32_16x16x32_bf16(af, bf, acc[dt], 0, 0, 0);
    }
  }
  // full row-sums: reduce the 4 quads holding row m
  S += __shfl_xor(S, 16);
  S += __shfl_xor(S, 32);
  float* ob = hcat + (size_t)b * N_ * 256 + h * 64 + m;
#pragma unroll
  for (int r = 0; r < 4; r++) {
    const float invS = 1.0f / __shfl(S, q * 4 + r);  // C/D row = q*4+r lives in lane (q*4+r) of quad 0
    float* op = ob + (size_t)(i0 + q * 4 + r) * 256;
    op[0]  = acc[0][r] * invS;
    op[16] = acc[1][r] * invS;
    op[32] = acc[2][r] * invS;
    op[48] = acc[3][r] * invS;
  }
}

// ---- K3: h2 = hcat @ W_out (K=256); s2/t2; h2T bf16 transposed [b*64+d][j]
__global__ __launch_bounds__(256) void gat_k3(
    const float* __restrict__ hcat, const float* __restrict__ Wo, const float* __restrict__ ao,
    unsigned short* __restrict__ h2T, float* __restrict__ s2, float* __restrict__ t2) {
  __shared__ float xs[32 * 256];  // 32 KB
  __shared__ float hl[32 * 65];   // 8.3 KB
  const int b = blockIdx.y, n0 = blockIdx.x * 32;
  const int tid = threadIdx.x;
  const float4* xg = (const float4*)(hcat + ((size_t)b * N_ + n0) * 256);
  float4* xs4 = (float4*)xs;
  for (int i = tid; i < 32 * 256 / 4; i += 256) xs4[i] = xg[i];
  __syncthreads();
  const int d = tid & 63, g = tid >> 6;
  const float* Wp = Wo + d;
  float acc[8];
#pragma unroll
  for (int n = 0; n < 8; n++) acc[n] = 0.f;
  for (int k4 = 0; k4 < 64; k4++) {
    const float w0 = Wp[(k4 * 4 + 0) * 64];
    const float w1 = Wp[(k4 * 4 + 1) * 64];
    const float w2 = Wp[(k4 * 4 + 2) * 64];
    const float w3 = Wp[(k4 * 4 + 3) * 64];
#pragma unroll
    for (int n = 0; n < 8; n++) {
      float4 xv = xs4[(g * 8 + n) * 64 + k4];
      acc[n] = fmaf(xv.x, w0, acc[n]);
      acc[n] = fmaf(xv.y, w1, acc[n]);
      acc[n] = fmaf(xv.z, w2, acc[n]);
      acc[n] = fmaf(xv.w, w3, acc[n]);
    }
  }
#pragma unroll
  for (int n = 0; n < 8; n++) hl[(g * 8 + n) * 65 + d] = acc[n];
  __syncthreads();
  if (tid < 32) {
    const int n = tid;
    float sa = 0.f, ta = 0.f;
#pragma unroll 8
    for (int dd = 0; dd < 64; dd++) {
      const float hv = hl[n * 65 + dd];
      sa = fmaf(hv, ao[dd], sa);
      ta = fmaf(hv, ao[64 + dd], ta);
    }
    s2[b * N_ + n0 + n] = sa;
    t2[b * N_ + n0 + n] = ta;
  }
  unsigned int u[4];
#pragma unroll
  for (int i = 0; i < 4; i++) {
    const int n = g * 8 + 2 * i;
    u[i] = f2b_bits(hl[n * 65 + d]) | (f2b_bits(hl[(n + 1) * 65 + d]) << 16);
  }
  unsigned int* dst = (unsigned int*)h2T + (size_t)(b * 64 + d) * (N_ / 2) + n0 / 2 + g * 4;
  *(uint4*)dst = make_uint4(u[0], u[1], u[2], u[3]);
}

// ---- K4: layer-2 attention (single head). Block = 4 waves = 4 distinct 16-row i-tiles.
__global__ __launch_bounds__(256) void gat_k4(
    const int* __restrict__ adj, const unsigned short* __restrict__ h2T,
    const float* __restrict__ s2, const float* __restrict__ t2, float* __restrict__ out) {
  const int b = blockIdx.y;
  const int tid = threadIdx.x;
  const int wv = tid >> 6, lane = tid & 63;
  const int i0 = blockIdx.x * 64 + wv * 16;
  const int m = lane & 15, q = lane >> 4;
  const float s_i = s2[b * N_ + i0 + m];
  const int* ap = adj + ((size_t)b * N_ + i0 + m) * N_ + q * 8;
  const float* tp = t2 + b * N_ + q * 8;
  const unsigned short* vp = h2T + (size_t)(b * 64 + m) * N_ + q * 8;
  float4v acc[4] = {};
  float S = 0.f;
  for (int j0 = 0; j0 < N_; j0 += 32) {
    const int4 a0 = *(const int4*)(ap + j0);
    const int4 a1 = *(const int4*)(ap + j0 + 4);
    const float4 tv0 = *(const float4*)(tp + j0);
    const float4 tv1 = *(const float4*)(tp + j0 + 4);
    const float tv[8] = {tv0.x, tv0.y, tv0.z, tv0.w, tv1.x, tv1.y, tv1.z, tv1.w};
    const int av[8] = {a0.x, a0.y, a0.z, a0.w, a1.x, a1.y, a1.z, a1.w};
    float w[8];
#pragma unroll
    for (int i = 0; i < 8; i++) {
      float e = s_i + tv[i];
      e = fmaxf(e, 0.2f * e);
      w[i] = av[i] ? __expf(e) : 0.f;
    }
    S += ((w[0] + w[1]) + (w[2] + w[3])) + ((w[4] + w[5]) + (w[6] + w[7]));
    short8 af;
#pragma unroll
    for (int i = 0; i < 8; i++) af[i] = (short)f2b_bits(w[i]);
#pragma unroll
    for (int dt = 0; dt < 4; dt++) {
      const short8 bf = *(const short8*)(vp + (size_t)dt * 16 * N_ + j0);
      acc[dt] = __builtin_amdgcn_mfma_f32_16x16x32_bf16(af, bf, acc[dt], 0, 0, 0);
    }
  }
  S += __shfl_xor(S, 16);
  S += __shfl_xor(S, 32);
  float* ob = out + (size_t)b * N_ * 64 + m;
#pragma unroll
  for (int r = 0; r < 4; r++) {
    const float invS = 1.0f / __shfl(S, q * 4 + r);
    float* op = ob + (size_t)(i0 + q * 4 + r) * 64;
    op[0]  = acc[0][r] * invS;
    op[16] = acc[1][r] * invS;
    op[32] = acc[2][r] * invS;
    op[48] = acc[3][r] * invS;
  }
}

extern "C" void kernel_launch(void* const* d_in, const int* in_sizes, int n_in,
                              void* d_out, int out_size, void* d_ws, size_t ws_size,
                              hipStream_t stream) {
  (void)in_sizes; (void)n_in; (void)out_size; (void)ws_size;
  const float* x  = (const float*)d_in[0];
  const int* adj  = (const int*)d_in[1];
  const float* Wh = (const float*)d_in[2];
  const float* ah = (const float*)d_in[3];
  const float* Wo = (const float*)d_in[4];
  const float* ao = (const float*)d_in[5];
  float* out = (float*)d_out;

  // workspace layout (~14 MB), all 16B-aligned offsets
  char* p = (char*)d_ws;
  unsigned short* h1T = (unsigned short*)p; p += (size_t)B_ * NH_ * 64 * N_ * 2;  // 4 MB
  float* s1 = (float*)p;   p += (size_t)B_ * NH_ * N_ * 4;                        // 128 KB
  float* t1 = (float*)p;   p += (size_t)B_ * NH_ * N_ * 4;                        // 128 KB
  float* hcat = (float*)p; p += (size_t)B_ * N_ * 256 * 4;                        // 8 MB
  unsigned short* h2T = (unsigned short*)p; p += (size_t)B_ * 64 * N_ * 2;        // 1 MB
  float* s2 = (float*)p;   p += (size_t)B_ * N_ * 4;                              // 32 KB
  float* t2 = (float*)p;   p += (size_t)B_ * N_ * 4;                              // 32 KB

  gat_k1<<<dim3(N_ / 32, B_), 256, 0, stream>>>(x, Wh, ah, h1T, s1, t1);
  gat_k2<<<dim3(N_ / 16, B_), 256, 0, stream>>>(adj, h1T, s1, t1, hcat);
  gat_k3<<<dim3(N_ / 32, B_), 256, 0, stream>>>(hcat, Wo, ao, h2T, s2, t2);
  gat_k4<<<dim3(N_ / 64, B_), 256, 0, stream>>>(adj, h2T, s2, t2, out);
}

// Round 2
// 272.990 us; speedup vs baseline: 1.0637x; 1.0637x over previous
//
#include <hip/hip_runtime.h>

// GAT: B=4, N=2048, IN=128, HID=64, HEADS=4, OUT=64
// R2: j-split attention (occupancy 8->16 waves/CU), partial-softmax combine
//     fused into k3 (layer1) / tiny k5 (layer2), v_perm bf16 pack, unroll 2.
#define B_ 4
#define N_ 2048
#define IND_ 128
#define NH_ 4

typedef short short8 __attribute__((ext_vector_type(8)));
typedef float float4v __attribute__((ext_vector_type(4)));

// fp32 -> bf16 bits, round-to-nearest-even (cold paths: h1T/h2T pack)
__device__ __forceinline__ unsigned int f2b_bits(float f) {
  unsigned int u = __float_as_uint(f);
  u += 0x7fffu + ((u >> 16) & 1u);
  return u >> 16;
}

// hot path: truncating pack of two fp32 -> (bf16(hi)<<16)|bf16(lo), 1 v_perm_b32
__device__ __forceinline__ unsigned int pack_trunc(float lo, float hi) {
  return __builtin_amdgcn_perm(__float_as_uint(hi), __float_as_uint(lo), 0x07060302u);
}

// ---- K1: h1[head] = x @ W_heads[head]; s1/t1 = h1 . a_heads halves;
//      h1T = bf16 transposed V operand, layout [(b*4+h)*64 + d][j]
__global__ __launch_bounds__(256) void gat_k1(
    const float* __restrict__ x, const float* __restrict__ Wh, const float* __restrict__ ah,
    unsigned short* __restrict__ h1T, float* __restrict__ s1, float* __restrict__ t1) {
  __shared__ float xs[32 * IND_];
  __shared__ float hl[32 * 257];
  const int b = blockIdx.y, n0 = blockIdx.x * 32;
  const int tid = threadIdx.x;
  const float4* xg = (const float4*)(x + ((size_t)b * N_ + n0) * IND_);
  float4* xs4 = (float4*)xs;
  for (int i = tid; i < 32 * IND_ / 4; i += 256) xs4[i] = xg[i];
  __syncthreads();
  const int h = tid >> 6, d = tid & 63;
  const float* Wp = Wh + h * IND_ * 64 + d;
  float acc[32];
#pragma unroll
  for (int n = 0; n < 32; n++) acc[n] = 0.f;
  for (int k4 = 0; k4 < IND_ / 4; k4++) {
    const float w0 = Wp[(k4 * 4 + 0) * 64];
    const float w1 = Wp[(k4 * 4 + 1) * 64];
    const float w2 = Wp[(k4 * 4 + 2) * 64];
    const float w3 = Wp[(k4 * 4 + 3) * 64];
#pragma unroll
    for (int n = 0; n < 32; n++) {
      float4 xv = xs4[n * (IND_ / 4) + k4];
      acc[n] = fmaf(xv.x, w0, acc[n]);
      acc[n] = fmaf(xv.y, w1, acc[n]);
      acc[n] = fmaf(xv.z, w2, acc[n]);
      acc[n] = fmaf(xv.w, w3, acc[n]);
    }
  }
#pragma unroll
  for (int n = 0; n < 32; n++) hl[n * 257 + tid] = acc[n];
  __syncthreads();
  if (tid < 128) {
    const int n = tid & 31, hh = tid >> 5;
    const float* hp = hl + n * 257 + hh * 64;
    const float* a1 = ah + hh * 128;
    float sa = 0.f, ta = 0.f;
#pragma unroll 8
    for (int dd = 0; dd < 64; dd++) {
      const float hv = hp[dd];
      sa = fmaf(hv, a1[dd], sa);
      ta = fmaf(hv, a1[64 + dd], ta);
    }
    s1[(b * NH_ + hh) * N_ + n0 + n] = sa;
    t1[(b * NH_ + hh) * N_ + n0 + n] = ta;
  }
  unsigned int u[16];
#pragma unroll
  for (int i = 0; i < 16; i++)
    u[i] = f2b_bits(hl[(2 * i) * 257 + tid]) | (f2b_bits(hl[(2 * i + 1) * 257 + tid]) << 16);
  unsigned int* dst = (unsigned int*)h1T + (size_t)(b * 256 + tid) * (N_ / 2) + n0 / 2;
#pragma unroll
  for (int g = 0; g < 4; g++)
    ((uint4*)dst)[g] = make_uint4(u[4 * g], u[4 * g + 1], u[4 * g + 2], u[4 * g + 3]);
}

// ---- K2: layer-1 attention, j-split 2. Block = 4 waves = 4 heads, same i-tile+j-half
//      (adj L1 reuse). Writes UNnormalized numerator partial + row-sum partial.
__global__ __launch_bounds__(256) void gat_k2(
    const int* __restrict__ adj, const unsigned short* __restrict__ h1T,
    const float* __restrict__ s1, const float* __restrict__ t1,
    float* __restrict__ p1, float* __restrict__ S1p) {
  const int b = blockIdx.z, js = blockIdx.y, i0 = blockIdx.x * 16;
  const int tid = threadIdx.x;
  const int h = tid >> 6, lane = tid & 63;
  const int m = lane & 15, q = lane >> 4;
  const int jbase = js * (N_ / 2);
  const float s_i = s1[(b * NH_ + h) * N_ + i0 + m];
  const int* ap = adj + ((size_t)b * N_ + i0 + m) * N_ + jbase + q * 8;
  const float* tp = t1 + (b * NH_ + h) * N_ + jbase + q * 8;
  const unsigned short* vp = h1T + (size_t)((b * NH_ + h) * 64 + m) * N_ + jbase + q * 8;
  float4v acc[4] = {};
  float S = 0.f;
#pragma unroll 2
  for (int j0 = 0; j0 < N_ / 2; j0 += 32) {
    const int4 a0 = *(const int4*)(ap + j0);
    const int4 a1 = *(const int4*)(ap + j0 + 4);
    const float4 tv0 = *(const float4*)(tp + j0);
    const float4 tv1 = *(const float4*)(tp + j0 + 4);
    const float tv[8] = {tv0.x, tv0.y, tv0.z, tv0.w, tv1.x, tv1.y, tv1.z, tv1.w};
    const int av[8] = {a0.x, a0.y, a0.z, a0.w, a1.x, a1.y, a1.z, a1.w};
    float w[8];
#pragma unroll
    for (int i = 0; i < 8; i++) {
      float e = s_i + tv[i];
      e = fmaxf(e, 0.2f * e);
      w[i] = av[i] ? __expf(e) : 0.f;
    }
    S += ((w[0] + w[1]) + (w[2] + w[3])) + ((w[4] + w[5]) + (w[6] + w[7]));
    union { unsigned int u[4]; short8 v; } cvt;
#pragma unroll
    for (int i = 0; i < 4; i++) cvt.u[i] = pack_trunc(w[2 * i], w[2 * i + 1]);
    const short8 af = cvt.v;
#pragma unroll
    for (int dt = 0; dt < 4; dt++) {
      const short8 bf = *(const short8*)(vp + (size_t)dt * 16 * N_ + j0);
      acc[dt] = __builtin_amdgcn_mfma_f32_16x16x32_bf16(af, bf, acc[dt], 0, 0, 0);
    }
  }
  S += __shfl_xor(S, 16);
  S += __shfl_xor(S, 32);
  if (lane < 16) S1p[((js * B_ + b) * NH_ + h) * N_ + i0 + m] = S;
  float* ob = p1 + (size_t)(js * B_ + b) * N_ * 256 + h * 64 + m;
#pragma unroll
  for (int r = 0; r < 4; r++) {
    float* op = ob + (size_t)(i0 + q * 4 + r) * 256;
    op[0]  = acc[0][r];
    op[16] = acc[1][r];
    op[32] = acc[2][r];
    op[48] = acc[3][r];
  }
}

// ---- K3: fused layer-1 combine + h2 = hcat @ W_out (K=256); s2/t2; h2T pack.
//      hcat never materialized: tile = (p1[0]+p1[1]) * 1/(S0+S1) on the fly.
__global__ __launch_bounds__(256) void gat_k3(
    const float* __restrict__ p1, const float* __restrict__ S1p,
    const float* __restrict__ Wo, const float* __restrict__ ao,
    unsigned short* __restrict__ h2T, float* __restrict__ s2, float* __restrict__ t2) {
  __shared__ float xs[32 * 256];
  __shared__ float hl[32 * 65];
  __shared__ float sInv[32][4];
  const int b = blockIdx.y, n0 = blockIdx.x * 32;
  const int tid = threadIdx.x;
  if (tid < 128) {
    const int n = tid & 31, hh = tid >> 5;
    const float Sv = S1p[((0 * B_ + b) * NH_ + hh) * N_ + n0 + n] +
                     S1p[((1 * B_ + b) * NH_ + hh) * N_ + n0 + n];
    sInv[n][hh] = 1.0f / Sv;
  }
  __syncthreads();
  const float4* g0 = (const float4*)(p1 + ((size_t)(0 * B_ + b) * N_ + n0) * 256);
  const float4* g1 = (const float4*)(p1 + ((size_t)(1 * B_ + b) * N_ + n0) * 256);
  float4* xs4 = (float4*)xs;
  for (int i = tid; i < 32 * 256 / 4; i += 256) {
    const float4 v0 = g0[i], v1 = g1[i];
    const int n = i >> 6, hh = (i & 63) >> 4;
    const float iv = sInv[n][hh];
    float4 r;
    r.x = (v0.x + v1.x) * iv;
    r.y = (v0.y + v1.y) * iv;
    r.z = (v0.z + v1.z) * iv;
    r.w = (v0.w + v1.w) * iv;
    xs4[i] = r;
  }
  __syncthreads();
  const int d = tid & 63, g = tid >> 6;
  const float* Wp = Wo + d;
  float acc[8];
#pragma unroll
  for (int n = 0; n < 8; n++) acc[n] = 0.f;
  for (int k4 = 0; k4 < 64; k4++) {
    const float w0 = Wp[(k4 * 4 + 0) * 64];
    const float w1 = Wp[(k4 * 4 + 1) * 64];
    const float w2 = Wp[(k4 * 4 + 2) * 64];
    const float w3 = Wp[(k4 * 4 + 3) * 64];
#pragma unroll
    for (int n = 0; n < 8; n++) {
      float4 xv = xs4[(g * 8 + n) * 64 + k4];
      acc[n] = fmaf(xv.x, w0, acc[n]);
      acc[n] = fmaf(xv.y, w1, acc[n]);
      acc[n] = fmaf(xv.z, w2, acc[n]);
      acc[n] = fmaf(xv.w, w3, acc[n]);
    }
  }
#pragma unroll
  for (int n = 0; n < 8; n++) hl[(g * 8 + n) * 65 + d] = acc[n];
  __syncthreads();
  if (tid < 32) {
    const int n = tid;
    float sa = 0.f, ta = 0.f;
#pragma unroll 8
    for (int dd = 0; dd < 64; dd++) {
      const float hv = hl[n * 65 + dd];
      sa = fmaf(hv, ao[dd], sa);
      ta = fmaf(hv, ao[64 + dd], ta);
    }
    s2[b * N_ + n0 + n] = sa;
    t2[b * N_ + n0 + n] = ta;
  }
  unsigned int u[4];
#pragma unroll
  for (int i = 0; i < 4; i++) {
    const int n = g * 8 + 2 * i;
    u[i] = f2b_bits(hl[n * 65 + d]) | (f2b_bits(hl[(n + 1) * 65 + d]) << 16);
  }
  unsigned int* dst = (unsigned int*)h2T + (size_t)(b * 64 + d) * (N_ / 2) + n0 / 2 + g * 4;
  *(uint4*)dst = make_uint4(u[0], u[1], u[2], u[3]);
}

// ---- K4: layer-2 attention, j-split 8. Block = 4 waves = 4 i-tiles, same j-slice.
//      8-iter loop; writes numerator partial + S partial.
__global__ __launch_bounds__(256) void gat_k4(
    const int* __restrict__ adj, const unsigned short* __restrict__ h2T,
    const float* __restrict__ s2, const float* __restrict__ t2,
    float* __restrict__ p2, float* __restrict__ S2p) {
  const int b = blockIdx.z, js = blockIdx.y;
  const int tid = threadIdx.x;
  const int wv = tid >> 6, lane = tid & 63;
  const int i0 = (blockIdx.x * 4 + wv) * 16;
  const int m = lane & 15, q = lane >> 4;
  const int jbase = js * (N_ / 8);
  const float s_i = s2[b * N_ + i0 + m];
  const int* ap = adj + ((size_t)b * N_ + i0 + m) * N_ + jbase + q * 8;
  const float* tp = t2 + b * N_ + jbase + q * 8;
  const unsigned short* vp = h2T + (size_t)(b * 64 + m) * N_ + jbase + q * 8;
  float4v acc[4] = {};
  float S = 0.f;
#pragma unroll 2
  for (int j0 = 0; j0 < N_ / 8; j0 += 32) {
    const int4 a0 = *(const int4*)(ap + j0);
    const int4 a1 = *(const int4*)(ap + j0 + 4);
    const float4 tv0 = *(const float4*)(tp + j0);
    const float4 tv1 = *(const float4*)(tp + j0 + 4);
    const float tv[8] = {tv0.x, tv0.y, tv0.z, tv0.w, tv1.x, tv1.y, tv1.z, tv1.w};
    const int av[8] = {a0.x, a0.y, a0.z, a0.w, a1.x, a1.y, a1.z, a1.w};
    float w[8];
#pragma unroll
    for (int i = 0; i < 8; i++) {
      float e = s_i + tv[i];
      e = fmaxf(e, 0.2f * e);
      w[i] = av[i] ? __expf(e) : 0.f;
    }
    S += ((w[0] + w[1]) + (w[2] + w[3])) + ((w[4] + w[5]) + (w[6] + w[7]));
    union { unsigned int u[4]; short8 v; } cvt;
#pragma unroll
    for (int i = 0; i < 4; i++) cvt.u[i] = pack_trunc(w[2 * i], w[2 * i + 1]);
    const short8 af = cvt.v;
#pragma unroll
    for (int dt = 0; dt < 4; dt++) {
      const short8 bf = *(const short8*)(vp + (size_t)dt * 16 * N_ + j0);
      acc[dt] = __builtin_amdgcn_mfma_f32_16x16x32_bf16(af, bf, acc[dt], 0, 0, 0);
    }
  }
  S += __shfl_xor(S, 16);
  S += __shfl_xor(S, 32);
  if (lane < 16) S2p[(js * B_ + b) * N_ + i0 + m] = S;
  float* ob = p2 + (size_t)(js * B_ + b) * N_ * 64 + m;
#pragma unroll
  for (int r = 0; r < 4; r++) {
    float* op = ob + (size_t)(i0 + q * 4 + r) * 64;
    op[0]  = acc[0][r];
    op[16] = acc[1][r];
    op[32] = acc[2][r];
    op[48] = acc[3][r];
  }
}

// ---- K5: layer-2 combine: out = sum_s p2[s] / sum_s S2p[s]
__global__ __launch_bounds__(256) void gat_k5(
    const float* __restrict__ p2, const float* __restrict__ S2p, float* __restrict__ out) {
  const int gid = blockIdx.x * 256 + threadIdx.x;  // 131072 total
  const int row = gid >> 4, c4 = gid & 15;         // row = b*N+i
  float S = 0.f;
  float4 acc = make_float4(0.f, 0.f, 0.f, 0.f);
  const float4* pr = (const float4*)p2 + (size_t)row * 16 + c4;
#pragma unroll
  for (int s = 0; s < 8; s++) {
    S += S2p[(size_t)s * B_ * N_ + row];
    const float4 v = pr[(size_t)s * B_ * N_ * 16];
    acc.x += v.x; acc.y += v.y; acc.z += v.z; acc.w += v.w;
  }
  const float iv = 1.0f / S;
  acc.x *= iv; acc.y *= iv; acc.z *= iv; acc.w *= iv;
  ((float4*)out)[gid] = acc;
}

extern "C" void kernel_launch(void* const* d_in, const int* in_sizes, int n_in,
                              void* d_out, int out_size, void* d_ws, size_t ws_size,
                              hipStream_t stream) {
  (void)in_sizes; (void)n_in; (void)out_size; (void)ws_size;
  const float* x  = (const float*)d_in[0];
  const int* adj  = (const int*)d_in[1];
  const float* Wh = (const float*)d_in[2];
  const float* ah = (const float*)d_in[3];
  const float* Wo = (const float*)d_in[4];
  const float* ao = (const float*)d_in[5];
  float* out = (float*)d_out;

  // workspace layout (~22 MB); p2/S2p alias the [h1T..p1] region (dead by k4)
  char* base = (char*)d_ws;
  char* p = base;
  unsigned short* h1T = (unsigned short*)p; p += (size_t)B_ * NH_ * 64 * N_ * 2;  // 4 MB
  float* s1 = (float*)p;  p += (size_t)B_ * NH_ * N_ * 4;                         // 128 KB
  float* t1 = (float*)p;  p += (size_t)B_ * NH_ * N_ * 4;                         // 128 KB
  float* p1 = (float*)p;  p += (size_t)2 * B_ * N_ * 256 * 4;                     // 16 MB
  float* S1p = (float*)p; p += (size_t)2 * B_ * NH_ * N_ * 4;                     // 256 KB
  unsigned short* h2T = (unsigned short*)p; p += (size_t)B_ * 64 * N_ * 2;        // 1 MB
  float* s2 = (float*)p;  p += (size_t)B_ * N_ * 4;                               // 32 KB
  float* t2 = (float*)p;  p += (size_t)B_ * N_ * 4;                               // 32 KB
  float* p2  = (float*)base;                                  // 16 MB, aliases h1T/s1/t1/p1
  float* S2p = (float*)(base + (size_t)16 * 1024 * 1024);     // 256 KB, still inside old p1

  gat_k1<<<dim3(N_ / 32, B_), 256, 0, stream>>>(x, Wh, ah, h1T, s1, t1);
  gat_k2<<<dim3(N_ / 16, 2, B_), 256, 0, stream>>>(adj, h1T, s1, t1, p1, S1p);
  gat_k3<<<dim3(N_ / 32, B_), 256, 0, stream>>>(p1, S1p, Wo, ao, h2T, s2, t2);
  gat_k4<<<dim3(N_ / 64, 8, B_), 256, 0, stream>>>(adj, h2T, s2, t2, p2, S2p);
  gat_k5<<<dim3(B_ * N_ * 64 / 1024), 256, 0, stream>>>(p2, S2p, out);
}

// Round 3
// 212.812 us; speedup vs baseline: 1.3644x; 1.2828x over previous
//
#include <hip/hip_runtime.h>

// GAT: B=4, N=2048, IN=128, HID=64, HEADS=4, OUT=64
// R3: adj bit-pack (2MB, L2-resident); k2/k4 restructured: 4 waves = 4 i-tiles of
// one head, V staged via global_load_lds double-buffer (4x fewer line transactions);
// exp factored out of inner loop (per-node exp pairs, cndmask select); softmax
// denominator via ones-column MFMA (per-lane, no shuffles); k2 full-j -> writes
// normalized hcat directly (no layer-1 partials).
#define B_ 4
#define N_ 2048
#define IND_ 128
#define NH_ 4

typedef short short8 __attribute__((ext_vector_type(8)));
typedef float float4v __attribute__((ext_vector_type(4)));

#if __has_builtin(__builtin_amdgcn_sbfe)
#define SBFE(x, o) __builtin_amdgcn_sbfe((int)(x), (unsigned)(o), 1u)
#else
#define SBFE(x, o) (((int)((unsigned)(x) << (31 - (o)))) >> 31)
#endif

typedef __attribute__((address_space(1))) const unsigned int as1_u32;
typedef __attribute__((address_space(3))) unsigned int as3_u32;
__device__ __forceinline__ void gl_lds16(const void* g, void* l) {
  __builtin_amdgcn_global_load_lds((as1_u32*)g, (as3_u32*)l, 16, 0, 0);
}

// fp32 -> bf16 bits, RNE (cold paths)
__device__ __forceinline__ unsigned int f2b_bits(float f) {
  unsigned int u = __float_as_uint(f);
  u += 0x7fffu + ((u >> 16) & 1u);
  return u >> 16;
}
// truncating pack of two fp32 -> packed bf16 pair, 1 v_perm
__device__ __forceinline__ unsigned int pack_trunc(float lo, float hi) {
  return __builtin_amdgcn_perm(__float_as_uint(hi), __float_as_uint(lo), 0x07060302u);
}

// ---- K0: adj int32 -> bitmask (bit j of row (b,i)); 2 MB, L2-resident
__global__ __launch_bounds__(256) void gat_k0(
    const int* __restrict__ adj, unsigned long long* __restrict__ adjm) {
  const int gid = blockIdx.x * 256 + threadIdx.x;
  const unsigned long long mval = __ballot(adj[gid] != 0);
  if ((threadIdx.x & 63) == 0) adjm[gid >> 6] = mval;
}

// ---- K1: h1 = x @ W_heads; exp-pair s/t terms; h1T bf16 transposed [(b*4+h)*64+d][j]
__global__ __launch_bounds__(256) void gat_k1(
    const float* __restrict__ x, const float* __restrict__ Wh, const float* __restrict__ ah,
    unsigned short* __restrict__ h1T, float2* __restrict__ Es1, float2* __restrict__ Et1) {
  __shared__ float xs[32 * IND_];
  __shared__ float hl[32 * 257];
  const int b = blockIdx.y, n0 = blockIdx.x * 32;
  const int tid = threadIdx.x;
  const float4* xg = (const float4*)(x + ((size_t)b * N_ + n0) * IND_);
  float4* xs4 = (float4*)xs;
  for (int i = tid; i < 32 * IND_ / 4; i += 256) xs4[i] = xg[i];
  __syncthreads();
  const int h = tid >> 6, d = tid & 63;
  const float* Wp = Wh + h * IND_ * 64 + d;
  float acc[32];
#pragma unroll
  for (int n = 0; n < 32; n++) acc[n] = 0.f;
  for (int k4 = 0; k4 < IND_ / 4; k4++) {
    const float w0 = Wp[(k4 * 4 + 0) * 64];
    const float w1 = Wp[(k4 * 4 + 1) * 64];
    const float w2 = Wp[(k4 * 4 + 2) * 64];
    const float w3 = Wp[(k4 * 4 + 3) * 64];
#pragma unroll
    for (int n = 0; n < 32; n++) {
      float4 xv = xs4[n * (IND_ / 4) + k4];
      acc[n] = fmaf(xv.x, w0, acc[n]);
      acc[n] = fmaf(xv.y, w1, acc[n]);
      acc[n] = fmaf(xv.z, w2, acc[n]);
      acc[n] = fmaf(xv.w, w3, acc[n]);
    }
  }
#pragma unroll
  for (int n = 0; n < 32; n++) hl[n * 257 + tid] = acc[n];
  __syncthreads();
  if (tid < 128) {
    const int n = tid & 31, hh = tid >> 5;
    const float* hp = hl + n * 257 + hh * 64;
    const float* a1 = ah + hh * 128;
    float sa = 0.f, ta = 0.f;
#pragma unroll 8
    for (int dd = 0; dd < 64; dd++) {
      const float hv = hp[dd];
      sa = fmaf(hv, a1[dd], sa);
      ta = fmaf(hv, a1[64 + dd], ta);
    }
    Es1[(b * NH_ + hh) * N_ + n0 + n] = make_float2(__expf(sa), __expf(0.2f * sa));
    Et1[(b * NH_ + hh) * N_ + n0 + n] = make_float2(__expf(ta), __expf(0.2f * ta));
  }
  unsigned int u[16];
#pragma unroll
  for (int i = 0; i < 16; i++)
    u[i] = f2b_bits(hl[(2 * i) * 257 + tid]) | (f2b_bits(hl[(2 * i + 1) * 257 + tid]) << 16);
  unsigned int* dst = (unsigned int*)h1T + (size_t)(b * 256 + tid) * (N_ / 2) + n0 / 2;
#pragma unroll
  for (int g = 0; g < 4; g++)
    ((uint4*)dst)[g] = make_uint4(u[4 * g], u[4 * g + 1], u[4 * g + 2], u[4 * g + 3]);
}

// ---- K2: layer-1 attention, full-j. Block = 4 waves = 4 i-tiles (64 rows), one head.
// V staged to LDS (global_load_lds, dbuf); E pairs staged once; S via ones-MFMA;
// writes normalized hcat directly.
__global__ __launch_bounds__(256) void gat_k2(
    const unsigned char* __restrict__ adjm, const unsigned short* __restrict__ h1T,
    const float2* __restrict__ Es1, const float2* __restrict__ Et1,
    float* __restrict__ hcat) {
  __shared__ float4 Ebuf[1024];     // 16 KB: (E1,E2) pairs for all 2048 j
  __shared__ uint4 vbuf[2][256];    // 2 x 4 KB V chunks (64 d x 32 j bf16)
  const int b = blockIdx.z, h = blockIdx.y;
  const int tid = threadIdx.x;
  const int wv = tid >> 6, lane = tid & 63;
  const int m = lane & 15, q = lane >> 4;
  const int i0 = blockIdx.x * 64 + wv * 16;
  const int hb = b * NH_ + h;
  {
    const char* esrc = (const char*)(Et1 + (size_t)hb * N_);
    char* edst = (char*)Ebuf;
#pragma unroll
    for (int c = 0; c < 4; c++)
      gl_lds16(esrc + c * 4096 + tid * 16, edst + c * 4096 + tid * 16);
  }
  const char* vsrc = (const char*)(h1T + ((size_t)hb * 64 + (tid >> 2)) * N_) + (tid & 3) * 16;
  gl_lds16(vsrc, (char*)vbuf[0] + tid * 16);
  const float2 G = Es1[(size_t)hb * N_ + i0 + m];
  const float G1 = G.x, G2 = G.y;
  const float NSE = 1.0f / G1;  // exp(-s_i)
  const unsigned char* mrow = adjm + (size_t)(b * N_ + i0 + m) * (N_ / 8);
  const int q8 = q * 8;
  float4v acc[4] = {};
  float4v accS = {};
  const short8 ONES = {0x3F80, 0x3F80, 0x3F80, 0x3F80, 0x3F80, 0x3F80, 0x3F80, 0x3F80};
  uint4 mw = *(const uint4*)mrow;  // mask dwords for iters 0..3
  for (int it4 = 0; it4 < 16; it4++) {
#pragma unroll
    for (int s = 0; s < 4; s++) {
      const int it = it4 * 4 + s;
      __syncthreads();  // vbuf[it&1] landed; prev readers done
      if (it + 1 < 64) gl_lds16(vsrc + (it + 1) * 64, (char*)vbuf[(it + 1) & 1] + tid * 16);
      const unsigned mword = s == 0 ? mw.x : s == 1 ? mw.y : s == 2 ? mw.z : mw.w;
      if (s == 3 && it4 < 15) mw = *(const uint4*)(mrow + (it4 + 1) * 16);
      const float4* ep = Ebuf + it * 16 + q * 4;
      unsigned pk[4];
#pragma unroll
      for (int p = 0; p < 4; p++) {
        const float4 e2 = ep[p];
        const bool c0 = e2.x >= NSE;
        const bool c1 = e2.z >= NSE;
        float w0 = (c0 ? G1 : G2) * (c0 ? e2.x : e2.y);
        float w1 = (c1 ? G1 : G2) * (c1 ? e2.z : e2.w);
        const int a0 = SBFE(mword, q8 + 2 * p);
        const int a1 = SBFE(mword, q8 + 2 * p + 1);
        pk[p] = pack_trunc(__uint_as_float(__float_as_uint(w0) & (unsigned)a0),
                           __uint_as_float(__float_as_uint(w1) & (unsigned)a1));
      }
      union { unsigned u[4]; short8 v; } cu;
      cu.u[0] = pk[0]; cu.u[1] = pk[1]; cu.u[2] = pk[2]; cu.u[3] = pk[3];
      const char* curv = (const char*)vbuf[it & 1];
#pragma unroll
      for (int dt = 0; dt < 4; dt++) {
        const short8 bf = *(const short8*)(curv + (dt * 16 + m) * 64 + q * 16);
        acc[dt] = __builtin_amdgcn_mfma_f32_16x16x32_bf16(cu.v, bf, acc[dt], 0, 0, 0);
      }
      accS = __builtin_amdgcn_mfma_f32_16x16x32_bf16(cu.v, ONES, accS, 0, 0, 0);
    }
  }
  float* ob = hcat + (size_t)b * N_ * 256 + h * 64 + m;
#pragma unroll
  for (int r = 0; r < 4; r++) {
    const float invS = 1.0f / accS[r];  // row sum lives per-lane in C-layout
    float* op = ob + (size_t)(i0 + q * 4 + r) * 256;
    op[0]  = acc[0][r] * invS;
    op[16] = acc[1][r] * invS;
    op[32] = acc[2][r] * invS;
    op[48] = acc[3][r] * invS;
  }
}

// ---- K3: h2 = hcat @ W_out (K=256); exp pairs; h2T bf16 transposed [b*64+d][j]
__global__ __launch_bounds__(256) void gat_k3(
    const float* __restrict__ hcat, const float* __restrict__ Wo, const float* __restrict__ ao,
    unsigned short* __restrict__ h2T, float2* __restrict__ Es2, float2* __restrict__ Et2) {
  __shared__ float xs[32 * 256];
  __shared__ float hl[32 * 65];
  const int b = blockIdx.y, n0 = blockIdx.x * 32;
  const int tid = threadIdx.x;
  const float4* xg = (const float4*)(hcat + ((size_t)b * N_ + n0) * 256);
  float4* xs4 = (float4*)xs;
  for (int i = tid; i < 32 * 256 / 4; i += 256) xs4[i] = xg[i];
  __syncthreads();
  const int d = tid & 63, g = tid >> 6;
  const float* Wp = Wo + d;
  float acc[8];
#pragma unroll
  for (int n = 0; n < 8; n++) acc[n] = 0.f;
  for (int k4 = 0; k4 < 64; k4++) {
    const float w0 = Wp[(k4 * 4 + 0) * 64];
    const float w1 = Wp[(k4 * 4 + 1) * 64];
    const float w2 = Wp[(k4 * 4 + 2) * 64];
    const float w3 = Wp[(k4 * 4 + 3) * 64];
#pragma unroll
    for (int n = 0; n < 8; n++) {
      float4 xv = xs4[(g * 8 + n) * 64 + k4];
      acc[n] = fmaf(xv.x, w0, acc[n]);
      acc[n] = fmaf(xv.y, w1, acc[n]);
      acc[n] = fmaf(xv.z, w2, acc[n]);
      acc[n] = fmaf(xv.w, w3, acc[n]);
    }
  }
#pragma unroll
  for (int n = 0; n < 8; n++) hl[(g * 8 + n) * 65 + d] = acc[n];
  __syncthreads();
  if (tid < 32) {
    const int n = tid;
    float sa = 0.f, ta = 0.f;
#pragma unroll 8
    for (int dd = 0; dd < 64; dd++) {
      const float hv = hl[n * 65 + dd];
      sa = fmaf(hv, ao[dd], sa);
      ta = fmaf(hv, ao[64 + dd], ta);
    }
    Es2[b * N_ + n0 + n] = make_float2(__expf(sa), __expf(0.2f * sa));
    Et2[b * N_ + n0 + n] = make_float2(__expf(ta), __expf(0.2f * ta));
  }
  unsigned int u[4];
#pragma unroll
  for (int i = 0; i < 4; i++) {
    const int n = g * 8 + 2 * i;
    u[i] = f2b_bits(hl[n * 65 + d]) | (f2b_bits(hl[(n + 1) * 65 + d]) << 16);
  }
  unsigned int* dst = (unsigned int*)h2T + (size_t)(b * 64 + d) * (N_ / 2) + n0 / 2 + g * 4;
  *(uint4*)dst = make_uint4(u[0], u[1], u[2], u[3]);
}

// ---- K4: layer-2 attention, js=4 split. Block = 4 waves = 4 i-tiles, one j-slice.
// Same engine as k2; writes unnormalized partials + S partials.
__global__ __launch_bounds__(256) void gat_k4(
    const unsigned char* __restrict__ adjm, const unsigned short* __restrict__ h2T,
    const float2* __restrict__ Es2, const float2* __restrict__ Et2,
    float* __restrict__ p2, float* __restrict__ S2p) {
  __shared__ float4 Ebuf[256];      // 4 KB: E pairs for this 512-j slice
  __shared__ uint4 vbuf[2][256];
  const int b = blockIdx.z, js = blockIdx.y;
  const int tid = threadIdx.x;
  const int wv = tid >> 6, lane = tid & 63;
  const int m = lane & 15, q = lane >> 4;
  const int i0 = blockIdx.x * 64 + wv * 16;
  gl_lds16((const char*)(Et2 + (size_t)b * N_ + js * 512) + tid * 16,
           (char*)Ebuf + tid * 16);
  const char* vsrc = (const char*)(h2T + ((size_t)b * 64 + (tid >> 2)) * N_) +
                     (size_t)js * 1024 + (tid & 3) * 16;
  gl_lds16(vsrc, (char*)vbuf[0] + tid * 16);
  const float2 G = Es2[(size_t)b * N_ + i0 + m];
  const float G1 = G.x, G2 = G.y;
  const float NSE = 1.0f / G1;
  const unsigned char* mrow = adjm + (size_t)(b * N_ + i0 + m) * (N_ / 8) + js * 64;
  const int q8 = q * 8;
  float4v acc[4] = {};
  float4v accS = {};
  const short8 ONES = {0x3F80, 0x3F80, 0x3F80, 0x3F80, 0x3F80, 0x3F80, 0x3F80, 0x3F80};
  uint4 mw = *(const uint4*)mrow;
  for (int it4 = 0; it4 < 4; it4++) {
#pragma unroll
    for (int s = 0; s < 4; s++) {
      const int it = it4 * 4 + s;
      __syncthreads();
      if (it + 1 < 16) gl_lds16(vsrc + (it + 1) * 64, (char*)vbuf[(it + 1) & 1] + tid * 16);
      const unsigned mword = s == 0 ? mw.x : s == 1 ? mw.y : s == 2 ? mw.z : mw.w;
      if (s == 3 && it4 < 3) mw = *(const uint4*)(mrow + (it4 + 1) * 16);
      const float4* ep = Ebuf + it * 16 + q * 4;
      unsigned pk[4];
#pragma unroll
      for (int p = 0; p < 4; p++) {
        const float4 e2 = ep[p];
        const bool c0 = e2.x >= NSE;
        const bool c1 = e2.z >= NSE;
        float w0 = (c0 ? G1 : G2) * (c0 ? e2.x : e2.y);
        float w1 = (c1 ? G1 : G2) * (c1 ? e2.z : e2.w);
        const int a0 = SBFE(mword, q8 + 2 * p);
        const int a1 = SBFE(mword, q8 + 2 * p + 1);
        pk[p] = pack_trunc(__uint_as_float(__float_as_uint(w0) & (unsigned)a0),
                           __uint_as_float(__float_as_uint(w1) & (unsigned)a1));
      }
      union { unsigned u[4]; short8 v; } cu;
      cu.u[0] = pk[0]; cu.u[1] = pk[1]; cu.u[2] = pk[2]; cu.u[3] = pk[3];
      const char* curv = (const char*)vbuf[it & 1];
#pragma unroll
      for (int dt = 0; dt < 4; dt++) {
        const short8 bf = *(const short8*)(curv + (dt * 16 + m) * 64 + q * 16);
        acc[dt] = __builtin_amdgcn_mfma_f32_16x16x32_bf16(cu.v, bf, acc[dt], 0, 0, 0);
      }
      accS = __builtin_amdgcn_mfma_f32_16x16x32_bf16(cu.v, ONES, accS, 0, 0, 0);
    }
  }
  if (m == 0) {
#pragma unroll
    for (int r = 0; r < 4; r++)
      S2p[(size_t)(js * B_ + b) * N_ + i0 + q * 4 + r] = accS[r];
  }
  float* ob = p2 + (size_t)(js * B_ + b) * N_ * 64 + m;
#pragma unroll
  for (int r = 0; r < 4; r++) {
    float* op = ob + (size_t)(i0 + q * 4 + r) * 64;
    op[0]  = acc[0][r];
    op[16] = acc[1][r];
    op[32] = acc[2][r];
    op[48] = acc[3][r];
  }
}

// ---- K5: layer-2 combine over 4 j-slices
__global__ __launch_bounds__(256) void gat_k5(
    const float* __restrict__ p2, const float* __restrict__ S2p, float* __restrict__ out) {
  const int gid = blockIdx.x * 256 + threadIdx.x;  // 131072
  const int row = gid >> 4, c4 = gid & 15;
  float S = 0.f;
  float4 acc = make_float4(0.f, 0.f, 0.f, 0.f);
  const float4* pr = (const float4*)p2 + (size_t)row * 16 + c4;
#pragma unroll
  for (int s = 0; s < 4; s++) {
    S += S2p[(size_t)s * B_ * N_ + row];
    const float4 v = pr[(size_t)s * B_ * N_ * 16];
    acc.x += v.x; acc.y += v.y; acc.z += v.z; acc.w += v.w;
  }
  const float iv = 1.0f / S;
  acc.x *= iv; acc.y *= iv; acc.z *= iv; acc.w *= iv;
  ((float4*)out)[gid] = acc;
}

extern "C" void kernel_launch(void* const* d_in, const int* in_sizes, int n_in,
                              void* d_out, int out_size, void* d_ws, size_t ws_size,
                              hipStream_t stream) {
  (void)in_sizes; (void)n_in; (void)out_size; (void)ws_size;
  const float* x  = (const float*)d_in[0];
  const int* adj  = (const int*)d_in[1];
  const float* Wh = (const float*)d_in[2];
  const float* ah = (const float*)d_in[3];
  const float* Wo = (const float*)d_in[4];
  const float* ao = (const float*)d_in[5];
  float* out = (float*)d_out;

  // workspace layout, 16.5 MB total (proven-safe; R2 used 21.6 MB)
  char* base = (char*)d_ws;
  unsigned long long* adjm = (unsigned long long*)base;        // 2 MB  [0, 2M)
  unsigned short* h1T = (unsigned short*)(base + 2097152);     // 4 MB  [2M, 6M)
  float2* Et1 = (float2*)(base + 6291456);                     // 256 KB
  float2* Es1 = (float2*)(base + 6553600);                     // 256 KB
  unsigned short* h2T = (unsigned short*)(base + 6815744);     // 1 MB
  float2* Et2 = (float2*)(base + 7864320);                     // 64 KB
  float2* Es2 = (float2*)(base + 7929856);                     // 64 KB
  float* hcat = (float*)(base + 7995392);                      // 8 MB (dead after k3)
  float* p2   = hcat;                                          // 8 MB alias (k4 -> k5)
  float* S2p  = (float*)(base + 7995392 + 8388608);            // 128 KB

  gat_k0<<<dim3(B_ * N_ * N_ / 256), 256, 0, stream>>>(adj, adjm);
  gat_k1<<<dim3(N_ / 32, B_), 256, 0, stream>>>(x, Wh, ah, h1T, Es1, Et1);
  gat_k2<<<dim3(N_ / 64, NH_, B_), 256, 0, stream>>>(
      (const unsigned char*)adjm, h1T, Es1, Et1, hcat);
  gat_k3<<<dim3(N_ / 32, B_), 256, 0, stream>>>(hcat, Wo, ao, h2T, Es2, Et2);
  gat_k4<<<dim3(N_ / 64, 4, B_), 256, 0, stream>>>(
      (const unsigned char*)adjm, h2T, Es2, Et2, p2, S2p);
  gat_k5<<<dim3(B_ * N_ * 64 / 1024), 256, 0, stream>>>(p2, S2p, out);
}

// Round 4
// 178.002 us; speedup vs baseline: 1.6313x; 1.1956x over previous
//
#include <hip/hip_runtime.h>

// GAT: B=4, N=2048, IN=128, HID=64, HEADS=4, OUT=64
// R4: k1/k3 rewritten as bf16-MFMA GEMMs with hi/lo split (fp32-accurate);
// W pre-packed to B-frag layout + v_s/v_t = W@a vectors in prep blocks fused
// into k0; s,t = x.(W@a) computed exactly in fp32 from LDS x-tile.
// k2/k4/k5 unchanged from R3.
#define B_ 4
#define N_ 2048
#define IND_ 128
#define NH_ 4

typedef short short8 __attribute__((ext_vector_type(8)));
typedef float float4v __attribute__((ext_vector_type(4)));

#if __has_builtin(__builtin_amdgcn_sbfe)
#define SBFE(x, o) __builtin_amdgcn_sbfe((int)(x), (unsigned)(o), 1u)
#else
#define SBFE(x, o) (((int)((unsigned)(x) << (31 - (o)))) >> 31)
#endif

typedef __attribute__((address_space(1))) const unsigned int as1_u32;
typedef __attribute__((address_space(3))) unsigned int as3_u32;
__device__ __forceinline__ void gl_lds16(const void* g, void* l) {
  __builtin_amdgcn_global_load_lds((as1_u32*)g, (as3_u32*)l, 16, 0, 0);
}

// fp32 -> bf16 bits, RNE
__device__ __forceinline__ unsigned int f2b_bits(float f) {
  unsigned int u = __float_as_uint(f);
  u += 0x7fffu + ((u >> 16) & 1u);
  return u >> 16;
}
// RNE pack of two fp32 -> (bf16(hi)<<16)|bf16(lo)
__device__ __forceinline__ unsigned int pack_rne(float lo, float hi) {
  return f2b_bits(lo) | (f2b_bits(hi) << 16);
}
// truncating pack, 1 v_perm
__device__ __forceinline__ unsigned int pack_trunc(float lo, float hi) {
  return __builtin_amdgcn_perm(__float_as_uint(hi), __float_as_uint(lo), 0x07060302u);
}
// truncate-to-bf16 as fp32 (exact residual base)
__device__ __forceinline__ float trunc_bf(float f) {
  return __uint_as_float(__float_as_uint(f) & 0xFFFF0000u);
}

union u4s8 { uint4 u; short8 s; };

// ---- K0: adj bitmask + (extra blocks) W packing and v=W@a vectors
__global__ __launch_bounds__(256) void gat_k0(
    const int* __restrict__ adj, unsigned long long* __restrict__ adjm,
    const float* __restrict__ Wh, const float* __restrict__ ah,
    const float* __restrict__ Wo, const float* __restrict__ ao,
    uint4* __restrict__ Wpk1, uint4* __restrict__ Wpk3,
    float* __restrict__ vsp1, float* __restrict__ vsp3) {
  const int bid = blockIdx.x;
  const int t = threadIdx.x;
  if (bid < B_ * N_ * N_ / 256) {
    const int gid = bid * 256 + t;
    const unsigned long long mval = __ballot(adj[gid] != 0);
    if ((t & 63) == 0) adjm[gid >> 6] = mval;
    return;
  }
  const int pb = bid - B_ * N_ * N_ / 256;
  if (pb < 32) {  // Wpk1: B-frag pack of W_heads, hi/lo. e=((h*4+dt)*4+ks)*2+p
    const int id = pb * 256 + t, e = id >> 6, l = id & 63;
    const int p = e & 1, ks = (e >> 1) & 3, dt = (e >> 3) & 3, h = e >> 5;
    const int d = dt * 16 + (l & 15), kb = ks * 32 + (l >> 4) * 8;
    unsigned u[4];
#pragma unroll
    for (int i = 0; i < 4; i++) {
      float w0 = Wh[(size_t)(h * IND_ + kb + 2 * i) * 64 + d];
      float w1 = Wh[(size_t)(h * IND_ + kb + 2 * i + 1) * 64 + d];
      if (p) {
        w0 -= __uint_as_float(f2b_bits(w0) << 16);
        w1 -= __uint_as_float(f2b_bits(w1) << 16);
      }
      u[i] = pack_rne(w0, w1);
    }
    Wpk1[e * 64 + l] = make_uint4(u[0], u[1], u[2], u[3]);
  } else if (pb < 48) {  // Wpk3: W_out pack. e=(dt*8+ks)*2+p
    const int id = (pb - 32) * 256 + t, e = id >> 6, l = id & 63;
    const int p = e & 1, ks = (e >> 1) & 7, dt = e >> 4;
    const int d = dt * 16 + (l & 15), kb = ks * 32 + (l >> 4) * 8;
    unsigned u[4];
#pragma unroll
    for (int i = 0; i < 4; i++) {
      float w0 = Wo[(size_t)(kb + 2 * i) * 64 + d];
      float w1 = Wo[(size_t)(kb + 2 * i + 1) * 64 + d];
      if (p) {
        w0 -= __uint_as_float(f2b_bits(w0) << 16);
        w1 -= __uint_as_float(f2b_bits(w1) << 16);
      }
      u[i] = pack_rne(w0, w1);
    }
    Wpk3[e * 64 + l] = make_uint4(u[0], u[1], u[2], u[3]);
  } else if (pb < 52) {  // vsp1[h][vec][k] = sum_d Wh[h][k][d]*ah[h][vec*64+d]
    const int id = (pb - 48) * 256 + t;
    const int h = id >> 8, vec = (id >> 7) & 1, k = id & 127;
    const float* wr = Wh + (size_t)(h * IND_ + k) * 64;
    const float* av = ah + h * 128 + vec * 64;
    float s = 0.f;
#pragma unroll 8
    for (int d = 0; d < 64; d++) s = fmaf(wr[d], av[d], s);
    vsp1[(h * 2 + vec) * 128 + k] = s;
  } else {  // vsp3[vec][k] = sum_d Wo[k][d]*ao[vec*64+d]
    const int id = (pb - 52) * 256 + t;
    const int vec = id >> 8, k = id & 255;
    const float* wr = Wo + (size_t)k * 64;
    const float* av = ao + vec * 64;
    float s = 0.f;
#pragma unroll 8
    for (int d = 0; d < 64; d++) s = fmaf(wr[d], av[d], s);
    vsp3[vec * 256 + k] = s;
  }
}

// ---- K1: MFMA GEMM h1 = x@W (hi/lo split). Block: j-tile 16, 4 waves = 4 heads.
// C[j][d] per lane: j = j0+q*4+r (4 consecutive), d = dt*16+m -> dwordx2 to h1T.
__global__ __launch_bounds__(256) void gat_k1(
    const float* __restrict__ x, const uint4* __restrict__ Wpk1,
    const float* __restrict__ vsp1,
    unsigned short* __restrict__ h1T, float2* __restrict__ Es1, float2* __restrict__ Et1) {
  __shared__ float xf[16 * 132];            // fp32 x tile (pad 132)
  __shared__ unsigned short xhi[16 * 136];  // bf16 hi (pad 136)
  __shared__ unsigned short xlo[16 * 136];
  const int b = blockIdx.y, j0 = blockIdx.x * 16;
  const int tid = threadIdx.x;
  const int jr = tid >> 4, k0 = (tid & 15) * 8;
  const float4* xg = (const float4*)(x + ((size_t)b * N_ + j0 + jr) * IND_ + k0);
  const float4 v0 = xg[0], v1 = xg[1];
  *(float4*)(xf + jr * 132 + k0) = v0;
  *(float4*)(xf + jr * 132 + k0 + 4) = v1;
  {  // hi/lo convert of own 8 elems (no barrier needed: same-thread data)
    unsigned hu[4], lu[4];
    hu[0] = pack_trunc(v0.x, v0.y); hu[1] = pack_trunc(v0.z, v0.w);
    hu[2] = pack_trunc(v1.x, v1.y); hu[3] = pack_trunc(v1.z, v1.w);
    lu[0] = pack_trunc(v0.x - trunc_bf(v0.x), v0.y - trunc_bf(v0.y));
    lu[1] = pack_trunc(v0.z - trunc_bf(v0.z), v0.w - trunc_bf(v0.w));
    lu[2] = pack_trunc(v1.x - trunc_bf(v1.x), v1.y - trunc_bf(v1.y));
    lu[3] = pack_trunc(v1.z - trunc_bf(v1.z), v1.w - trunc_bf(v1.w));
    *(uint4*)(xhi + jr * 136 + k0) = make_uint4(hu[0], hu[1], hu[2], hu[3]);
    *(uint4*)(xlo + jr * 136 + k0) = make_uint4(lu[0], lu[1], lu[2], lu[3]);
  }
  __syncthreads();
  const int h = tid >> 6, lane = tid & 63;
  const int m = lane & 15, q = lane >> 4;
  float4v acc[4] = {};
  const unsigned short* ap = xhi + m * 136 + q * 8;
  const unsigned short* alp = xlo + m * 136 + q * 8;
#pragma unroll
  for (int ks = 0; ks < 4; ks++) {
    const short8 ahi = *(const short8*)(ap + ks * 32);
    const short8 alo = *(const short8*)(alp + ks * 32);
#pragma unroll
    for (int dt = 0; dt < 4; dt++) {
      u4s8 bh, bl;
      bh.u = Wpk1[(((h * 4 + dt) * 4 + ks) * 2 + 0) * 64 + lane];
      bl.u = Wpk1[(((h * 4 + dt) * 4 + ks) * 2 + 1) * 64 + lane];
      acc[dt] = __builtin_amdgcn_mfma_f32_16x16x32_bf16(ahi, bh.s, acc[dt], 0, 0, 0);
      acc[dt] = __builtin_amdgcn_mfma_f32_16x16x32_bf16(alo, bh.s, acc[dt], 0, 0, 0);
      acc[dt] = __builtin_amdgcn_mfma_f32_16x16x32_bf16(ahi, bl.s, acc[dt], 0, 0, 0);
    }
  }
  const int hb = b * NH_ + h;
#pragma unroll
  for (int dt = 0; dt < 4; dt++) {
    const uint2 uu = make_uint2(pack_rne(acc[dt][0], acc[dt][1]),
                                pack_rne(acc[dt][2], acc[dt][3]));
    *(uint2*)(h1T + (size_t)(hb * 64 + dt * 16 + m) * N_ + j0 + q * 4) = uu;
  }
  // s,t = x.(W@a): 4h x 2vec x 16j x 2half = 256 threads
  const int vec = (tid >> 5) & 1, jd = (tid >> 1) & 15, half = tid & 1;
  const float* xr = xf + jd * 132 + half * 64;
  const float* vr = vsp1 + (h * 2 + vec) * 128 + half * 64;
  float dot = 0.f;
#pragma unroll
  for (int kk = 0; kk < 64; kk += 4) {
    const float4 xa = *(const float4*)(xr + kk);
    const float4 va = *(const float4*)(vr + kk);
    dot = fmaf(xa.x, va.x, dot); dot = fmaf(xa.y, va.y, dot);
    dot = fmaf(xa.z, va.z, dot); dot = fmaf(xa.w, va.w, dot);
  }
  dot += __shfl_xor(dot, 1);
  if (half == 0) {
    const float2 ev = make_float2(__expf(dot), __expf(0.2f * dot));
    if (vec == 0) Es1[(size_t)hb * N_ + j0 + jd] = ev;
    else          Et1[(size_t)hb * N_ + j0 + jd] = ev;
  }
}

// ---- K2: layer-1 attention (unchanged from R3)
__global__ __launch_bounds__(256) void gat_k2(
    const unsigned char* __restrict__ adjm, const unsigned short* __restrict__ h1T,
    const float2* __restrict__ Es1, const float2* __restrict__ Et1,
    float* __restrict__ hcat) {
  __shared__ float4 Ebuf[1024];
  __shared__ uint4 vbuf[2][256];
  const int b = blockIdx.z, h = blockIdx.y;
  const int tid = threadIdx.x;
  const int wv = tid >> 6, lane = tid & 63;
  const int m = lane & 15, q = lane >> 4;
  const int i0 = blockIdx.x * 64 + wv * 16;
  const int hb = b * NH_ + h;
  {
    const char* esrc = (const char*)(Et1 + (size_t)hb * N_);
    char* edst = (char*)Ebuf;
#pragma unroll
    for (int c = 0; c < 4; c++)
      gl_lds16(esrc + c * 4096 + tid * 16, edst + c * 4096 + tid * 16);
  }
  const char* vsrc = (const char*)(h1T + ((size_t)hb * 64 + (tid >> 2)) * N_) + (tid & 3) * 16;
  gl_lds16(vsrc, (char*)vbuf[0] + tid * 16);
  const float2 G = Es1[(size_t)hb * N_ + i0 + m];
  const float G1 = G.x, G2 = G.y;
  const float NSE = 1.0f / G1;
  const unsigned char* mrow = adjm + (size_t)(b * N_ + i0 + m) * (N_ / 8);
  const int q8 = q * 8;
  float4v acc[4] = {};
  float4v accS = {};
  const short8 ONES = {0x3F80, 0x3F80, 0x3F80, 0x3F80, 0x3F80, 0x3F80, 0x3F80, 0x3F80};
  uint4 mw = *(const uint4*)mrow;
  for (int it4 = 0; it4 < 16; it4++) {
#pragma unroll
    for (int s = 0; s < 4; s++) {
      const int it = it4 * 4 + s;
      __syncthreads();
      if (it + 1 < 64) gl_lds16(vsrc + (it + 1) * 64, (char*)vbuf[(it + 1) & 1] + tid * 16);
      const unsigned mword = s == 0 ? mw.x : s == 1 ? mw.y : s == 2 ? mw.z : mw.w;
      if (s == 3 && it4 < 15) mw = *(const uint4*)(mrow + (it4 + 1) * 16);
      const float4* ep = Ebuf + it * 16 + q * 4;
      unsigned pk[4];
#pragma unroll
      for (int p = 0; p < 4; p++) {
        const float4 e2 = ep[p];
        const bool c0 = e2.x >= NSE;
        const bool c1 = e2.z >= NSE;
        float w0 = (c0 ? G1 : G2) * (c0 ? e2.x : e2.y);
        float w1 = (c1 ? G1 : G2) * (c1 ? e2.z : e2.w);
        const int a0 = SBFE(mword, q8 + 2 * p);
        const int a1 = SBFE(mword, q8 + 2 * p + 1);
        pk[p] = pack_trunc(__uint_as_float(__float_as_uint(w0) & (unsigned)a0),
                           __uint_as_float(__float_as_uint(w1) & (unsigned)a1));
      }
      union { unsigned u[4]; short8 v; } cu;
      cu.u[0] = pk[0]; cu.u[1] = pk[1]; cu.u[2] = pk[2]; cu.u[3] = pk[3];
      const char* curv = (const char*)vbuf[it & 1];
#pragma unroll
      for (int dt = 0; dt < 4; dt++) {
        const short8 bf = *(const short8*)(curv + (dt * 16 + m) * 64 + q * 16);
        acc[dt] = __builtin_amdgcn_mfma_f32_16x16x32_bf16(cu.v, bf, acc[dt], 0, 0, 0);
      }
      accS = __builtin_amdgcn_mfma_f32_16x16x32_bf16(cu.v, ONES, accS, 0, 0, 0);
    }
  }
  float* ob = hcat + (size_t)b * N_ * 256 + h * 64 + m;
#pragma unroll
  for (int r = 0; r < 4; r++) {
    const float invS = 1.0f / accS[r];
    float* op = ob + (size_t)(i0 + q * 4 + r) * 256;
    op[0]  = acc[0][r] * invS;
    op[16] = acc[1][r] * invS;
    op[32] = acc[2][r] * invS;
    op[48] = acc[3][r] * invS;
  }
}

// ---- K3: MFMA GEMM h2 = hcat@W_out (K=256, hi/lo split). Block: j-tile 16,
// 4 waves = 4 d-tiles. Same epilogue pattern as k1.
__global__ __launch_bounds__(256) void gat_k3(
    const float* __restrict__ hcat, const uint4* __restrict__ Wpk3,
    const float* __restrict__ vsp3,
    unsigned short* __restrict__ h2T, float2* __restrict__ Es2, float2* __restrict__ Et2) {
  __shared__ float xf[16 * 260];
  __shared__ unsigned short xhi[16 * 264];
  __shared__ unsigned short xlo[16 * 264];
  const int b = blockIdx.y, j0 = blockIdx.x * 16;
  const int tid = threadIdx.x;
  const int jr = tid >> 4, k0 = (tid & 15) * 16;
  const float4* xg = (const float4*)(hcat + ((size_t)b * N_ + j0 + jr) * 256 + k0);
  float4 v[4];
#pragma unroll
  for (int i = 0; i < 4; i++) v[i] = xg[i];
#pragma unroll
  for (int i = 0; i < 4; i++) *(float4*)(xf + jr * 260 + k0 + 4 * i) = v[i];
  {
    unsigned hu[8], lu[8];
#pragma unroll
    for (int i = 0; i < 4; i++) {
      hu[2 * i]     = pack_trunc(v[i].x, v[i].y);
      hu[2 * i + 1] = pack_trunc(v[i].z, v[i].w);
      lu[2 * i]     = pack_trunc(v[i].x - trunc_bf(v[i].x), v[i].y - trunc_bf(v[i].y));
      lu[2 * i + 1] = pack_trunc(v[i].z - trunc_bf(v[i].z), v[i].w - trunc_bf(v[i].w));
    }
    *(uint4*)(xhi + jr * 264 + k0)     = make_uint4(hu[0], hu[1], hu[2], hu[3]);
    *(uint4*)(xhi + jr * 264 + k0 + 8) = make_uint4(hu[4], hu[5], hu[6], hu[7]);
    *(uint4*)(xlo + jr * 264 + k0)     = make_uint4(lu[0], lu[1], lu[2], lu[3]);
    *(uint4*)(xlo + jr * 264 + k0 + 8) = make_uint4(lu[4], lu[5], lu[6], lu[7]);
  }
  __syncthreads();
  const int w = tid >> 6, lane = tid & 63;
  const int m = lane & 15, q = lane >> 4;
  float4v acc = {};
  const unsigned short* ap = xhi + m * 264 + q * 8;
  const unsigned short* alp = xlo + m * 264 + q * 8;
#pragma unroll
  for (int ks = 0; ks < 8; ks++) {
    const short8 ahi = *(const short8*)(ap + ks * 32);
    const short8 alo = *(const short8*)(alp + ks * 32);
    u4s8 bh, bl;
    bh.u = Wpk3[((w * 8 + ks) * 2 + 0) * 64 + lane];
    bl.u = Wpk3[((w * 8 + ks) * 2 + 1) * 64 + lane];
    acc = __builtin_amdgcn_mfma_f32_16x16x32_bf16(ahi, bh.s, acc, 0, 0, 0);
    acc = __builtin_amdgcn_mfma_f32_16x16x32_bf16(alo, bh.s, acc, 0, 0, 0);
    acc = __builtin_amdgcn_mfma_f32_16x16x32_bf16(ahi, bl.s, acc, 0, 0, 0);
  }
  {
    const uint2 uu = make_uint2(pack_rne(acc[0], acc[1]), pack_rne(acc[2], acc[3]));
    *(uint2*)(h2T + (size_t)(b * 64 + w * 16 + m) * N_ + j0 + q * 4) = uu;
  }
  // s,t: 2vec x 16j x 8seg = 256 threads
  const int vec = tid >> 7, jj = (tid >> 3) & 15, seg = tid & 7;
  const float* xr = xf + jj * 260 + seg * 4;
  const float* vr = vsp3 + vec * 256 + seg * 4;
  float dot = 0.f;
#pragma unroll
  for (int s = 0; s < 8; s++) {
    const float4 xa = *(const float4*)(xr + s * 32);
    const float4 va = *(const float4*)(vr + s * 32);
    dot = fmaf(xa.x, va.x, dot); dot = fmaf(xa.y, va.y, dot);
    dot = fmaf(xa.z, va.z, dot); dot = fmaf(xa.w, va.w, dot);
  }
  dot += __shfl_xor(dot, 1);
  dot += __shfl_xor(dot, 2);
  dot += __shfl_xor(dot, 4);
  if (seg == 0) {
    const float2 ev = make_float2(__expf(dot), __expf(0.2f * dot));
    if (vec == 0) Es2[(size_t)b * N_ + j0 + jj] = ev;
    else          Et2[(size_t)b * N_ + j0 + jj] = ev;
  }
}

// ---- K4: layer-2 attention, js=4 (unchanged from R3)
__global__ __launch_bounds__(256) void gat_k4(
    const unsigned char* __restrict__ adjm, const unsigned short* __restrict__ h2T,
    const float2* __restrict__ Es2, const float2* __restrict__ Et2,
    float* __restrict__ p2, float* __restrict__ S2p) {
  __shared__ float4 Ebuf[256];
  __shared__ uint4 vbuf[2][256];
  const int b = blockIdx.z, js = blockIdx.y;
  const int tid = threadIdx.x;
  const int wv = tid >> 6, lane = tid & 63;
  const int m = lane & 15, q = lane >> 4;
  const int i0 = blockIdx.x * 64 + wv * 16;
  gl_lds16((const char*)(Et2 + (size_t)b * N_ + js * 512) + tid * 16,
           (char*)Ebuf + tid * 16);
  const char* vsrc = (const char*)(h2T + ((size_t)b * 64 + (tid >> 2)) * N_) +
                     (size_t)js * 1024 + (tid & 3) * 16;
  gl_lds16(vsrc, (char*)vbuf[0] + tid * 16);
  const float2 G = Es2[(size_t)b * N_ + i0 + m];
  const float G1 = G.x, G2 = G.y;
  const float NSE = 1.0f / G1;
  const unsigned char* mrow = adjm + (size_t)(b * N_ + i0 + m) * (N_ / 8) + js * 64;
  const int q8 = q * 8;
  float4v acc[4] = {};
  float4v accS = {};
  const short8 ONES = {0x3F80, 0x3F80, 0x3F80, 0x3F80, 0x3F80, 0x3F80, 0x3F80, 0x3F80};
  uint4 mw = *(const uint4*)mrow;
  for (int it4 = 0; it4 < 4; it4++) {
#pragma unroll
    for (int s = 0; s < 4; s++) {
      const int it = it4 * 4 + s;
      __syncthreads();
      if (it + 1 < 16) gl_lds16(vsrc + (it + 1) * 64, (char*)vbuf[(it + 1) & 1] + tid * 16);
      const unsigned mword = s == 0 ? mw.x : s == 1 ? mw.y : s == 2 ? mw.z : mw.w;
      if (s == 3 && it4 < 3) mw = *(const uint4*)(mrow + (it4 + 1) * 16);
      const float4* ep = Ebuf + it * 16 + q * 4;
      unsigned pk[4];
#pragma unroll
      for (int p = 0; p < 4; p++) {
        const float4 e2 = ep[p];
        const bool c0 = e2.x >= NSE;
        const bool c1 = e2.z >= NSE;
        float w0 = (c0 ? G1 : G2) * (c0 ? e2.x : e2.y);
        float w1 = (c1 ? G1 : G2) * (c1 ? e2.z : e2.w);
        const int a0 = SBFE(mword, q8 + 2 * p);
        const int a1 = SBFE(mword, q8 + 2 * p + 1);
        pk[p] = pack_trunc(__uint_as_float(__float_as_uint(w0) & (unsigned)a0),
                           __uint_as_float(__float_as_uint(w1) & (unsigned)a1));
      }
      union { unsigned u[4]; short8 v; } cu;
      cu.u[0] = pk[0]; cu.u[1] = pk[1]; cu.u[2] = pk[2]; cu.u[3] = pk[3];
      const char* curv = (const char*)vbuf[it & 1];
#pragma unroll
      for (int dt = 0; dt < 4; dt++) {
        const short8 bf = *(const short8*)(curv + (dt * 16 + m) * 64 + q * 16);
        acc[dt] = __builtin_amdgcn_mfma_f32_16x16x32_bf16(cu.v, bf, acc[dt], 0, 0, 0);
      }
      accS = __builtin_amdgcn_mfma_f32_16x16x32_bf16(cu.v, ONES, accS, 0, 0, 0);
    }
  }
  if (m == 0) {
#pragma unroll
    for (int r = 0; r < 4; r++)
      S2p[(size_t)(js * B_ + b) * N_ + i0 + q * 4 + r] = accS[r];
  }
  float* ob = p2 + (size_t)(js * B_ + b) * N_ * 64 + m;
#pragma unroll
  for (int r = 0; r < 4; r++) {
    float* op = ob + (size_t)(i0 + q * 4 + r) * 64;
    op[0]  = acc[0][r];
    op[16] = acc[1][r];
    op[32] = acc[2][r];
    op[48] = acc[3][r];
  }
}

// ---- K5: layer-2 combine over 4 j-slices (unchanged)
__global__ __launch_bounds__(256) void gat_k5(
    const float* __restrict__ p2, const float* __restrict__ S2p, float* __restrict__ out) {
  const int gid = blockIdx.x * 256 + threadIdx.x;
  const int row = gid >> 4, c4 = gid & 15;
  float S = 0.f;
  float4 acc = make_float4(0.f, 0.f, 0.f, 0.f);
  const float4* pr = (const float4*)p2 + (size_t)row * 16 + c4;
#pragma unroll
  for (int s = 0; s < 4; s++) {
    S += S2p[(size_t)s * B_ * N_ + row];
    const float4 v = pr[(size_t)s * B_ * N_ * 16];
    acc.x += v.x; acc.y += v.y; acc.z += v.z; acc.w += v.w;
  }
  const float iv = 1.0f / S;
  acc.x *= iv; acc.y *= iv; acc.z *= iv; acc.w *= iv;
  ((float4*)out)[gid] = acc;
}

extern "C" void kernel_launch(void* const* d_in, const int* in_sizes, int n_in,
                              void* d_out, int out_size, void* d_ws, size_t ws_size,
                              hipStream_t stream) {
  (void)in_sizes; (void)n_in; (void)out_size; (void)ws_size;
  const float* x  = (const float*)d_in[0];
  const int* adj  = (const int*)d_in[1];
  const float* Wh = (const float*)d_in[2];
  const float* ah = (const float*)d_in[3];
  const float* Wo = (const float*)d_in[4];
  const float* ao = (const float*)d_in[5];
  float* out = (float*)d_out;

  // workspace layout (~16 MB)
  char* base = (char*)d_ws;
  unsigned long long* adjm = (unsigned long long*)base;        // 2 MB
  unsigned short* h1T = (unsigned short*)(base + 2097152);     // 4 MB
  float2* Et1 = (float2*)(base + 6291456);                     // 256 KB
  float2* Es1 = (float2*)(base + 6553600);                     // 256 KB
  unsigned short* h2T = (unsigned short*)(base + 6815744);     // 1 MB
  float2* Et2 = (float2*)(base + 7864320);                     // 64 KB
  float2* Es2 = (float2*)(base + 7929856);                     // 64 KB
  float* hcat = (float*)(base + 7995392);                      // 8 MB (dead after k3)
  float* p2   = hcat;                                          // alias (k4 -> k5)
  float* S2p  = (float*)(base + 16384000);                     // 128 KB
  uint4* Wpk1 = (uint4*)(base + 16512000);                     // 128 KB
  uint4* Wpk3 = (uint4*)(base + 16643072);                     // 64 KB
  float* vsp1 = (float*)(base + 16708608);                     // 4 KB
  float* vsp3 = (float*)(base + 16712704);                     // 2 KB

  gat_k0<<<dim3(B_ * N_ * N_ / 256 + 54), 256, 0, stream>>>(
      adj, adjm, Wh, ah, Wo, ao, Wpk1, Wpk3, vsp1, vsp3);
  gat_k1<<<dim3(N_ / 16, B_), 256, 0, stream>>>(x, Wpk1, vsp1, h1T, Es1, Et1);
  gat_k2<<<dim3(N_ / 64, NH_, B_), 256, 0, stream>>>(
      (const unsigned char*)adjm, h1T, Es1, Et1, hcat);
  gat_k3<<<dim3(N_ / 16, B_), 256, 0, stream>>>(hcat, Wpk3, vsp3, h2T, Es2, Et2);
  gat_k4<<<dim3(N_ / 64, 4, B_), 256, 0, stream>>>(
      (const unsigned char*)adjm, h2T, Es2, Et2, p2, S2p);
  gat_k5<<<dim3(B_ * N_ * 64 / 1024), 256, 0, stream>>>(p2, S2p, out);
}

// Round 5
// 169.285 us; speedup vs baseline: 1.7153x; 1.0515x over previous
//
#include <hip/hip_runtime.h>

// GAT: B=4, N=2048, IN=128, HID=64, HEADS=4, OUT=64
// R5: k2/k4 attention engine v2 — w = max(e^s*e^t, e^{0.2s}*e^{0.2t}) identity
// (no cmp/cndmask), 64-j chunks (half the barriers), XOR-swizzled V staging
// (2-way LDS banks), k2 j-split 2 (4 blocks/CU) with combine fused into k3.
#define B_ 4
#define N_ 2048
#define IND_ 128
#define NH_ 4

typedef short short8 __attribute__((ext_vector_type(8)));
typedef float float4v __attribute__((ext_vector_type(4)));

#if __has_builtin(__builtin_amdgcn_sbfe)
#define SBFE(x, o) __builtin_amdgcn_sbfe((int)(x), (unsigned)(o), 1u)
#else
#define SBFE(x, o) (((int)((unsigned)(x) << (31 - (o)))) >> 31)
#endif

typedef __attribute__((address_space(1))) const unsigned int as1_u32;
typedef __attribute__((address_space(3))) unsigned int as3_u32;
__device__ __forceinline__ void gl_lds16(const void* g, void* l) {
  __builtin_amdgcn_global_load_lds((as1_u32*)g, (as3_u32*)l, 16, 0, 0);
}

// fp32 -> bf16 bits, RNE
__device__ __forceinline__ unsigned int f2b_bits(float f) {
  unsigned int u = __float_as_uint(f);
  u += 0x7fffu + ((u >> 16) & 1u);
  return u >> 16;
}
__device__ __forceinline__ unsigned int pack_rne(float lo, float hi) {
  return f2b_bits(lo) | (f2b_bits(hi) << 16);
}
// truncating pack, 1 v_perm
__device__ __forceinline__ unsigned int pack_trunc(float lo, float hi) {
  return __builtin_amdgcn_perm(__float_as_uint(hi), __float_as_uint(lo), 0x07060302u);
}
__device__ __forceinline__ float trunc_bf(float f) {
  return __uint_as_float(__float_as_uint(f) & 0xFFFF0000u);
}

union u4s8 { uint4 u; short8 s; };

// ---- K0: adj bitmask + (extra blocks) W packing and v=W@a vectors
__global__ __launch_bounds__(256) void gat_k0(
    const int* __restrict__ adj, unsigned long long* __restrict__ adjm,
    const float* __restrict__ Wh, const float* __restrict__ ah,
    const float* __restrict__ Wo, const float* __restrict__ ao,
    uint4* __restrict__ Wpk1, uint4* __restrict__ Wpk3,
    float* __restrict__ vsp1, float* __restrict__ vsp3) {
  const int bid = blockIdx.x;
  const int t = threadIdx.x;
  if (bid < B_ * N_ * N_ / 256) {
    const int gid = bid * 256 + t;
    const unsigned long long mval = __ballot(adj[gid] != 0);
    if ((t & 63) == 0) adjm[gid >> 6] = mval;
    return;
  }
  const int pb = bid - B_ * N_ * N_ / 256;
  if (pb < 32) {  // Wpk1 B-frag pack (hi/lo)
    const int id = pb * 256 + t, e = id >> 6, l = id & 63;
    const int p = e & 1, ks = (e >> 1) & 3, dt = (e >> 3) & 3, h = e >> 5;
    const int d = dt * 16 + (l & 15), kb = ks * 32 + (l >> 4) * 8;
    unsigned u[4];
#pragma unroll
    for (int i = 0; i < 4; i++) {
      float w0 = Wh[(size_t)(h * IND_ + kb + 2 * i) * 64 + d];
      float w1 = Wh[(size_t)(h * IND_ + kb + 2 * i + 1) * 64 + d];
      if (p) {
        w0 -= __uint_as_float(f2b_bits(w0) << 16);
        w1 -= __uint_as_float(f2b_bits(w1) << 16);
      }
      u[i] = pack_rne(w0, w1);
    }
    Wpk1[e * 64 + l] = make_uint4(u[0], u[1], u[2], u[3]);
  } else if (pb < 48) {  // Wpk3 pack
    const int id = (pb - 32) * 256 + t, e = id >> 6, l = id & 63;
    const int p = e & 1, ks = (e >> 1) & 7, dt = e >> 4;
    const int d = dt * 16 + (l & 15), kb = ks * 32 + (l >> 4) * 8;
    unsigned u[4];
#pragma unroll
    for (int i = 0; i < 4; i++) {
      float w0 = Wo[(size_t)(kb + 2 * i) * 64 + d];
      float w1 = Wo[(size_t)(kb + 2 * i + 1) * 64 + d];
      if (p) {
        w0 -= __uint_as_float(f2b_bits(w0) << 16);
        w1 -= __uint_as_float(f2b_bits(w1) << 16);
      }
      u[i] = pack_rne(w0, w1);
    }
    Wpk3[e * 64 + l] = make_uint4(u[0], u[1], u[2], u[3]);
  } else if (pb < 52) {  // vsp1
    const int id = (pb - 48) * 256 + t;
    const int h = id >> 8, vec = (id >> 7) & 1, k = id & 127;
    const float* wr = Wh + (size_t)(h * IND_ + k) * 64;
    const float* av = ah + h * 128 + vec * 64;
    float s = 0.f;
#pragma unroll 8
    for (int d = 0; d < 64; d++) s = fmaf(wr[d], av[d], s);
    vsp1[(h * 2 + vec) * 128 + k] = s;
  } else {  // vsp3
    const int id = (pb - 52) * 256 + t;
    const int vec = id >> 8, k = id & 255;
    const float* wr = Wo + (size_t)k * 64;
    const float* av = ao + vec * 64;
    float s = 0.f;
#pragma unroll 8
    for (int d = 0; d < 64; d++) s = fmaf(wr[d], av[d], s);
    vsp3[vec * 256 + k] = s;
  }
}

// ---- K1: MFMA GEMM h1 = x@W (hi/lo split), unchanged from R4
__global__ __launch_bounds__(256) void gat_k1(
    const float* __restrict__ x, const uint4* __restrict__ Wpk1,
    const float* __restrict__ vsp1,
    unsigned short* __restrict__ h1T, float2* __restrict__ Es1, float2* __restrict__ Et1) {
  __shared__ float xf[16 * 132];
  __shared__ unsigned short xhi[16 * 136];
  __shared__ unsigned short xlo[16 * 136];
  const int b = blockIdx.y, j0 = blockIdx.x * 16;
  const int tid = threadIdx.x;
  const int jr = tid >> 4, k0 = (tid & 15) * 8;
  const float4* xg = (const float4*)(x + ((size_t)b * N_ + j0 + jr) * IND_ + k0);
  const float4 v0 = xg[0], v1 = xg[1];
  *(float4*)(xf + jr * 132 + k0) = v0;
  *(float4*)(xf + jr * 132 + k0 + 4) = v1;
  {
    unsigned hu[4], lu[4];
    hu[0] = pack_trunc(v0.x, v0.y); hu[1] = pack_trunc(v0.z, v0.w);
    hu[2] = pack_trunc(v1.x, v1.y); hu[3] = pack_trunc(v1.z, v1.w);
    lu[0] = pack_trunc(v0.x - trunc_bf(v0.x), v0.y - trunc_bf(v0.y));
    lu[1] = pack_trunc(v0.z - trunc_bf(v0.z), v0.w - trunc_bf(v0.w));
    lu[2] = pack_trunc(v1.x - trunc_bf(v1.x), v1.y - trunc_bf(v1.y));
    lu[3] = pack_trunc(v1.z - trunc_bf(v1.z), v1.w - trunc_bf(v1.w));
    *(uint4*)(xhi + jr * 136 + k0) = make_uint4(hu[0], hu[1], hu[2], hu[3]);
    *(uint4*)(xlo + jr * 136 + k0) = make_uint4(lu[0], lu[1], lu[2], lu[3]);
  }
  __syncthreads();
  const int h = tid >> 6, lane = tid & 63;
  const int m = lane & 15, q = lane >> 4;
  float4v acc[4] = {};
  const unsigned short* ap = xhi + m * 136 + q * 8;
  const unsigned short* alp = xlo + m * 136 + q * 8;
#pragma unroll
  for (int ks = 0; ks < 4; ks++) {
    const short8 ahi = *(const short8*)(ap + ks * 32);
    const short8 alo = *(const short8*)(alp + ks * 32);
#pragma unroll
    for (int dt = 0; dt < 4; dt++) {
      u4s8 bh, bl;
      bh.u = Wpk1[(((h * 4 + dt) * 4 + ks) * 2 + 0) * 64 + lane];
      bl.u = Wpk1[(((h * 4 + dt) * 4 + ks) * 2 + 1) * 64 + lane];
      acc[dt] = __builtin_amdgcn_mfma_f32_16x16x32_bf16(ahi, bh.s, acc[dt], 0, 0, 0);
      acc[dt] = __builtin_amdgcn_mfma_f32_16x16x32_bf16(alo, bh.s, acc[dt], 0, 0, 0);
      acc[dt] = __builtin_amdgcn_mfma_f32_16x16x32_bf16(ahi, bl.s, acc[dt], 0, 0, 0);
    }
  }
  const int hb = b * NH_ + h;
#pragma unroll
  for (int dt = 0; dt < 4; dt++) {
    const uint2 uu = make_uint2(pack_rne(acc[dt][0], acc[dt][1]),
                                pack_rne(acc[dt][2], acc[dt][3]));
    *(uint2*)(h1T + (size_t)(hb * 64 + dt * 16 + m) * N_ + j0 + q * 4) = uu;
  }
  const int vec = (tid >> 5) & 1, jd = (tid >> 1) & 15, half = tid & 1;
  const float* xr = xf + jd * 132 + half * 64;
  const float* vr = vsp1 + (h * 2 + vec) * 128 + half * 64;
  float dot = 0.f;
#pragma unroll
  for (int kk = 0; kk < 64; kk += 4) {
    const float4 xa = *(const float4*)(xr + kk);
    const float4 va = *(const float4*)(vr + kk);
    dot = fmaf(xa.x, va.x, dot); dot = fmaf(xa.y, va.y, dot);
    dot = fmaf(xa.z, va.z, dot); dot = fmaf(xa.w, va.w, dot);
  }
  dot += __shfl_xor(dot, 1);
  if (half == 0) {
    const float2 ev = make_float2(__expf(dot), __expf(0.2f * dot));
    if (vec == 0) Es1[(size_t)hb * N_ + j0 + jd] = ev;
    else          Et1[(size_t)hb * N_ + j0 + jd] = ev;
  }
}

// ---- K2: layer-1 attention v2. js=2 split; block = 4 waves = 4 i-tiles, one head.
// 64-j chunks, max-identity w, swizzled V staging. Writes partials p1 + S1p.
__global__ __launch_bounds__(256, 4) void gat_k2(
    const unsigned char* __restrict__ adjm, const unsigned short* __restrict__ h1T,
    const float2* __restrict__ Es1, const float2* __restrict__ Et1,
    float* __restrict__ p1, float* __restrict__ S1p) {
  __shared__ float4 Ebuf[512];     // 8 KB: E pairs for this 1024-j half
  __shared__ uint4 vbuf[2][512];   // 2 x 8 KB (64 j x 64 d bf16), XOR-swizzled rows
  const int b = blockIdx.z, h = blockIdx.y >> 1, js = blockIdx.y & 1;
  const int tid = threadIdx.x;
  const int wv = tid >> 6, lane = tid & 63;
  const int m = lane & 15, q = lane >> 4;
  const int i0 = blockIdx.x * 64 + wv * 16;
  const int hb = b * NH_ + h;
  const int jbase = js * 1024;
  {
    const char* esrc = (const char*)(Et1 + (size_t)hb * N_ + jbase);
    gl_lds16(esrc + tid * 16, (char*)Ebuf + tid * 16);
    gl_lds16(esrc + 4096 + tid * 16, (char*)Ebuf + 4096 + tid * 16);
  }
  // swizzle: LDS slot (d, s) holds global 16B piece s ^ (d&7) of row d
  const int pg = (tid & 7) ^ ((tid >> 3) & 7);
  const char* vsrc0 = (const char*)(h1T + ((size_t)hb * 64 + (tid >> 3)) * N_ + jbase) + pg * 16;
  const char* vsrc1 = (const char*)(h1T + ((size_t)hb * 64 + 32 + (tid >> 3)) * N_ + jbase) + pg * 16;
  gl_lds16(vsrc0, (char*)vbuf[0] + tid * 16);
  gl_lds16(vsrc1, (char*)vbuf[0] + 4096 + tid * 16);
  const float2 G = Es1[(size_t)hb * N_ + i0 + m];  // (e^s, e^{0.2s})
  const unsigned char* mrow = adjm + (size_t)(b * N_ + i0 + m) * (N_ / 8) + js * 128;
  float4v acc[4] = {};
  float4v accS = {};
  const short8 ONES = {0x3F80, 0x3F80, 0x3F80, 0x3F80, 0x3F80, 0x3F80, 0x3F80, 0x3F80};
  for (int it = 0; it < 16; it++) {
    __syncthreads();  // vbuf[it&1] landed; prev readers of vbuf[(it+1)&1] done
    if (it + 1 < 16) {
      gl_lds16(vsrc0 + (it + 1) * 128, (char*)vbuf[(it + 1) & 1] + tid * 16);
      gl_lds16(vsrc1 + (it + 1) * 128, (char*)vbuf[(it + 1) & 1] + 4096 + tid * 16);
    }
    const uint2 mw2 = *(const uint2*)(mrow + it * 8);
    const char* curv = (const char*)vbuf[it & 1];
#pragma unroll
    for (int c = 0; c < 2; c++) {
      const unsigned mword = c ? mw2.y : mw2.x;
      const float4* ep = Ebuf + it * 32 + c * 16 + q * 4;
      unsigned pk[4];
#pragma unroll
      for (int p = 0; p < 4; p++) {
        const float4 e2 = ep[p];
        // exp(leaky(s+t)) = max(e^s*e^t, e^{0.2s}*e^{0.2t})
        const float w0 = fmaxf(e2.x * G.x, e2.y * G.y);
        const float w1 = fmaxf(e2.z * G.x, e2.w * G.y);
        const int a0 = SBFE(mword, q * 8 + 2 * p);
        const int a1 = SBFE(mword, q * 8 + 2 * p + 1);
        pk[p] = pack_trunc(__uint_as_float(__float_as_uint(w0) & (unsigned)a0),
                           __uint_as_float(__float_as_uint(w1) & (unsigned)a1));
      }
      union { unsigned u[4]; short8 v; } cu;
      cu.u[0] = pk[0]; cu.u[1] = pk[1]; cu.u[2] = pk[2]; cu.u[3] = pk[3];
#pragma unroll
      for (int dt = 0; dt < 4; dt++) {
        const int d = dt * 16 + m;
        const short8 bf =
            *(const short8*)(curv + d * 128 + ((((c << 2) + q) ^ (m & 7)) << 4));
        acc[dt] = __builtin_amdgcn_mfma_f32_16x16x32_bf16(cu.v, bf, acc[dt], 0, 0, 0);
      }
      accS = __builtin_amdgcn_mfma_f32_16x16x32_bf16(cu.v, ONES, accS, 0, 0, 0);
    }
  }
  if (m == 0) {
#pragma unroll
    for (int r = 0; r < 4; r++)
      S1p[((js * B_ + b) * NH_ + h) * N_ + i0 + q * 4 + r] = accS[r];
  }
  float* ob = p1 + (size_t)(js * B_ + b) * N_ * 256 + h * 64 + m;
#pragma unroll
  for (int r = 0; r < 4; r++) {
    float* op = ob + (size_t)(i0 + q * 4 + r) * 256;
    op[0]  = acc[0][r];
    op[16] = acc[1][r];
    op[32] = acc[2][r];
    op[48] = acc[3][r];
  }
}

// ---- K3: fused layer-1 combine + MFMA GEMM h2 = hcat@W_out; exp pairs; h2T pack
__global__ __launch_bounds__(256) void gat_k3(
    const float* __restrict__ p1, const float* __restrict__ S1p,
    const uint4* __restrict__ Wpk3, const float* __restrict__ vsp3,
    unsigned short* __restrict__ h2T, float2* __restrict__ Es2, float2* __restrict__ Et2) {
  __shared__ float xf[16 * 260];
  __shared__ unsigned short xhi[16 * 264];
  __shared__ unsigned short xlo[16 * 264];
  __shared__ float sInv[16][4];
  const int b = blockIdx.y, j0 = blockIdx.x * 16;
  const int tid = threadIdx.x;
  if (tid < 64) {
    const int n = tid & 15, hh = tid >> 4;
    const float Sv = S1p[((0 * B_ + b) * NH_ + hh) * N_ + j0 + n] +
                     S1p[((1 * B_ + b) * NH_ + hh) * N_ + j0 + n];
    sInv[n][hh] = 1.0f / Sv;
  }
  __syncthreads();
  const int jr = tid >> 4, k0 = (tid & 15) * 16;
  const float4* g0 = (const float4*)(p1 + ((size_t)(0 * B_ + b) * N_ + j0 + jr) * 256 + k0);
  const float4* g1 = (const float4*)(p1 + ((size_t)(1 * B_ + b) * N_ + j0 + jr) * 256 + k0);
  const float iv = sInv[jr][k0 >> 6];
  float4 v[4];
#pragma unroll
  for (int i = 0; i < 4; i++) {
    const float4 a = g0[i], c = g1[i];
    v[i].x = (a.x + c.x) * iv; v[i].y = (a.y + c.y) * iv;
    v[i].z = (a.z + c.z) * iv; v[i].w = (a.w + c.w) * iv;
  }
#pragma unroll
  for (int i = 0; i < 4; i++) *(float4*)(xf + jr * 260 + k0 + 4 * i) = v[i];
  {
    unsigned hu[8], lu[8];
#pragma unroll
    for (int i = 0; i < 4; i++) {
      hu[2 * i]     = pack_trunc(v[i].x, v[i].y);
      hu[2 * i + 1] = pack_trunc(v[i].z, v[i].w);
      lu[2 * i]     = pack_trunc(v[i].x - trunc_bf(v[i].x), v[i].y - trunc_bf(v[i].y));
      lu[2 * i + 1] = pack_trunc(v[i].z - trunc_bf(v[i].z), v[i].w - trunc_bf(v[i].w));
    }
    *(uint4*)(xhi + jr * 264 + k0)     = make_uint4(hu[0], hu[1], hu[2], hu[3]);
    *(uint4*)(xhi + jr * 264 + k0 + 8) = make_uint4(hu[4], hu[5], hu[6], hu[7]);
    *(uint4*)(xlo + jr * 264 + k0)     = make_uint4(lu[0], lu[1], lu[2], lu[3]);
    *(uint4*)(xlo + jr * 264 + k0 + 8) = make_uint4(lu[4], lu[5], lu[6], lu[7]);
  }
  __syncthreads();
  const int w = tid >> 6, lane = tid & 63;
  const int m = lane & 15, q = lane >> 4;
  float4v acc = {};
  const unsigned short* ap = xhi + m * 264 + q * 8;
  const unsigned short* alp = xlo + m * 264 + q * 8;
#pragma unroll
  for (int ks = 0; ks < 8; ks++) {
    const short8 ahi = *(const short8*)(ap + ks * 32);
    const short8 alo = *(const short8*)(alp + ks * 32);
    u4s8 bh, bl;
    bh.u = Wpk3[((w * 8 + ks) * 2 + 0) * 64 + lane];
    bl.u = Wpk3[((w * 8 + ks) * 2 + 1) * 64 + lane];
    acc = __builtin_amdgcn_mfma_f32_16x16x32_bf16(ahi, bh.s, acc, 0, 0, 0);
    acc = __builtin_amdgcn_mfma_f32_16x16x32_bf16(alo, bh.s, acc, 0, 0, 0);
    acc = __builtin_amdgcn_mfma_f32_16x16x32_bf16(ahi, bl.s, acc, 0, 0, 0);
  }
  {
    const uint2 uu = make_uint2(pack_rne(acc[0], acc[1]), pack_rne(acc[2], acc[3]));
    *(uint2*)(h2T + (size_t)(b * 64 + w * 16 + m) * N_ + j0 + q * 4) = uu;
  }
  const int vec = tid >> 7, jj = (tid >> 3) & 15, seg = tid & 7;
  const float* xr = xf + jj * 260 + seg * 4;
  const float* vr = vsp3 + vec * 256 + seg * 4;
  float dot = 0.f;
#pragma unroll
  for (int s = 0; s < 8; s++) {
    const float4 xa = *(const float4*)(xr + s * 32);
    const float4 va = *(const float4*)(vr + s * 32);
    dot = fmaf(xa.x, va.x, dot); dot = fmaf(xa.y, va.y, dot);
    dot = fmaf(xa.z, va.z, dot); dot = fmaf(xa.w, va.w, dot);
  }
  dot += __shfl_xor(dot, 1);
  dot += __shfl_xor(dot, 2);
  dot += __shfl_xor(dot, 4);
  if (seg == 0) {
    const float2 ev = make_float2(__expf(dot), __expf(0.2f * dot));
    if (vec == 0) Es2[(size_t)b * N_ + j0 + jj] = ev;
    else          Et2[(size_t)b * N_ + j0 + jj] = ev;
  }
}

// ---- K4: layer-2 attention v2, js=8. Same engine as k2; partials p2 + S2p.
__global__ __launch_bounds__(256, 4) void gat_k4(
    const unsigned char* __restrict__ adjm, const unsigned short* __restrict__ h2T,
    const float2* __restrict__ Es2, const float2* __restrict__ Et2,
    float* __restrict__ p2, float* __restrict__ S2p) {
  __shared__ float4 Ebuf[128];     // 2 KB: E pairs for this 256-j slice
  __shared__ uint4 vbuf[2][512];   // 2 x 8 KB, swizzled
  const int b = blockIdx.z, js = blockIdx.y;
  const int tid = threadIdx.x;
  const int wv = tid >> 6, lane = tid & 63;
  const int m = lane & 15, q = lane >> 4;
  const int i0 = blockIdx.x * 64 + wv * 16;
  const int jbase = js * 256;
  if (tid < 128)
    gl_lds16((const char*)(Et2 + (size_t)b * N_ + jbase) + tid * 16,
             (char*)Ebuf + tid * 16);
  const int pg = (tid & 7) ^ ((tid >> 3) & 7);
  const char* vsrc0 = (const char*)(h2T + ((size_t)b * 64 + (tid >> 3)) * N_ + jbase) + pg * 16;
  const char* vsrc1 = (const char*)(h2T + ((size_t)b * 64 + 32 + (tid >> 3)) * N_ + jbase) + pg * 16;
  gl_lds16(vsrc0, (char*)vbuf[0] + tid * 16);
  gl_lds16(vsrc1, (char*)vbuf[0] + 4096 + tid * 16);
  const float2 G = Es2[(size_t)b * N_ + i0 + m];
  const unsigned char* mrow = adjm + (size_t)(b * N_ + i0 + m) * (N_ / 8) + js * 32;
  float4v acc[4] = {};
  float4v accS = {};
  const short8 ONES = {0x3F80, 0x3F80, 0x3F80, 0x3F80, 0x3F80, 0x3F80, 0x3F80, 0x3F80};
  for (int it = 0; it < 4; it++) {
    __syncthreads();
    if (it + 1 < 4) {
      gl_lds16(vsrc0 + (it + 1) * 128, (char*)vbuf[(it + 1) & 1] + tid * 16);
      gl_lds16(vsrc1 + (it + 1) * 128, (char*)vbuf[(it + 1) & 1] + 4096 + tid * 16);
    }
    const uint2 mw2 = *(const uint2*)(mrow + it * 8);
    const char* curv = (const char*)vbuf[it & 1];
#pragma unroll
    for (int c = 0; c < 2; c++) {
      const unsigned mword = c ? mw2.y : mw2.x;
      const float4* ep = Ebuf + it * 32 + c * 16 + q * 4;
      unsigned pk[4];
#pragma unroll
      for (int p = 0; p < 4; p++) {
        const float4 e2 = ep[p];
        const float w0 = fmaxf(e2.x * G.x, e2.y * G.y);
        const float w1 = fmaxf(e2.z * G.x, e2.w * G.y);
        const int a0 = SBFE(mword, q * 8 + 2 * p);
        const int a1 = SBFE(mword, q * 8 + 2 * p + 1);
        pk[p] = pack_trunc(__uint_as_float(__float_as_uint(w0) & (unsigned)a0),
                           __uint_as_float(__float_as_uint(w1) & (unsigned)a1));
      }
      union { unsigned u[4]; short8 v; } cu;
      cu.u[0] = pk[0]; cu.u[1] = pk[1]; cu.u[2] = pk[2]; cu.u[3] = pk[3];
#pragma unroll
      for (int dt = 0; dt < 4; dt++) {
        const int d = dt * 16 + m;
        const short8 bf =
            *(const short8*)(curv + d * 128 + ((((c << 2) + q) ^ (m & 7)) << 4));
        acc[dt] = __builtin_amdgcn_mfma_f32_16x16x32_bf16(cu.v, bf, acc[dt], 0, 0, 0);
      }
      accS = __builtin_amdgcn_mfma_f32_16x16x32_bf16(cu.v, ONES, accS, 0, 0, 0);
    }
  }
  if (m == 0) {
#pragma unroll
    for (int r = 0; r < 4; r++)
      S2p[(size_t)(js * B_ + b) * N_ + i0 + q * 4 + r] = accS[r];
  }
  float* ob = p2 + (size_t)(js * B_ + b) * N_ * 64 + m;
#pragma unroll
  for (int r = 0; r < 4; r++) {
    float* op = ob + (size_t)(i0 + q * 4 + r) * 64;
    op[0]  = acc[0][r];
    op[16] = acc[1][r];
    op[32] = acc[2][r];
    op[48] = acc[3][r];
  }
}

// ---- K5: layer-2 combine over 8 j-slices
__global__ __launch_bounds__(256) void gat_k5(
    const float* __restrict__ p2, const float* __restrict__ S2p, float* __restrict__ out) {
  const int gid = blockIdx.x * 256 + threadIdx.x;  // 131072
  const int row = gid >> 4, c4 = gid & 15;
  float S = 0.f;
  float4 acc = make_float4(0.f, 0.f, 0.f, 0.f);
  const float4* pr = (const float4*)p2 + (size_t)row * 16 + c4;
#pragma unroll
  for (int s = 0; s < 8; s++) {
    S += S2p[(size_t)s * B_ * N_ + row];
    const float4 v = pr[(size_t)s * B_ * N_ * 16];
    acc.x += v.x; acc.y += v.y; acc.z += v.z; acc.w += v.w;
  }
  const float iv = 1.0f / S;
  acc.x *= iv; acc.y *= iv; acc.z *= iv; acc.w *= iv;
  ((float4*)out)[gid] = acc;
}

extern "C" void kernel_launch(void* const* d_in, const int* in_sizes, int n_in,
                              void* d_out, int out_size, void* d_ws, size_t ws_size,
                              hipStream_t stream) {
  (void)in_sizes; (void)n_in; (void)out_size; (void)ws_size;
  const float* x  = (const float*)d_in[0];
  const int* adj  = (const int*)d_in[1];
  const float* Wh = (const float*)d_in[2];
  const float* ah = (const float*)d_in[3];
  const float* Wo = (const float*)d_in[4];
  const float* ao = (const float*)d_in[5];
  float* out = (float*)d_out;

  // workspace layout, 32 MB total
  char* base = (char*)d_ws;
  unsigned long long* adjm = (unsigned long long*)base;       // 2 MB
  unsigned short* h1T = (unsigned short*)(base + 0x200000);   // 4 MB
  float2* Et1 = (float2*)(base + 0x600000);                   // 256 KB
  float2* Es1 = (float2*)(base + 0x640000);                   // 256 KB
  unsigned short* h2T = (unsigned short*)(base + 0x680000);   // 1 MB
  float2* Et2 = (float2*)(base + 0x780000);                   // 64 KB
  float2* Es2 = (float2*)(base + 0x790000);                   // 64 KB
  float* S1p  = (float*)(base + 0x7A0000);                    // 256 KB
  float* S2p  = (float*)(base + 0x7E0000);                    // 256 KB
  uint4* Wpk1 = (uint4*)(base + 0x820000);                    // 128 KB
  uint4* Wpk3 = (uint4*)(base + 0x840000);                    // 64 KB
  float* vsp1 = (float*)(base + 0x850000);                    // 4 KB
  float* vsp3 = (float*)(base + 0x851000);                    // 2 KB
  float* p1   = (float*)(base + 0x1000000);                   // 16 MB [16M,32M)
  float* p2   = p1;                                           // alias (p1 dead after k3)

  gat_k0<<<dim3(B_ * N_ * N_ / 256 + 54), 256, 0, stream>>>(
      adj, adjm, Wh, ah, Wo, ao, Wpk1, Wpk3, vsp1, vsp3);
  gat_k1<<<dim3(N_ / 16, B_), 256, 0, stream>>>(x, Wpk1, vsp1, h1T, Es1, Et1);
  gat_k2<<<dim3(N_ / 64, NH_ * 2, B_), 256, 0, stream>>>(
      (const unsigned char*)adjm, h1T, Es1, Et1, p1, S1p);
  gat_k3<<<dim3(N_ / 16, B_), 256, 0, stream>>>(p1, S1p, Wpk3, vsp3, h2T, Es2, Et2);
  gat_k4<<<dim3(N_ / 64, 8, B_), 256, 0, stream>>>(
      (const unsigned char*)adjm, h2T, Es2, Et2, p2, S2p);
  gat_k5<<<dim3(B_ * N_ * 64 / 1024), 256, 0, stream>>>(p2, S2p, out);
}